// Round 3
// baseline (1156.479 us; speedup 1.0000x reference)
//
#include <hip/hip_runtime.h>
#include <stdint.h>

typedef __attribute__((ext_vector_type(8))) short short8;
typedef __attribute__((ext_vector_type(4))) float f32x4;
typedef unsigned short u16;
typedef unsigned int u32;

// ---------------- workspace layout (bytes) ----------------
#define WS_TOK   0ull           // tokens bf16 [32768][256]            16 MB
#define WS_XT    16777216ull    // x_t -> xm_tc -> r1 fp32 [T][C]      32 MB
#define WS_XMCT  50331648ull    // xm fp32 [C][T]                      32 MB
#define WS_GATES 83886080ull    // gates fp32 [T][8]                    1 MB
#define WS_PART  84934656ull    // bn partials [2][512][256] fp32       1 MB
#define WS_MOE   101711872ull   // moe fp32 [T][256]                   32 MB
#define WS_P1    135266304ull   // padded bf16 [34^3][256]             19.2MB
#define WS_P2    155389952ull
#define WS_Y     175513600ull   // conv out fp32 [T][256]              32 MB
#define WS_R2    209068032ull   // r2 bf16 [T][256]                    16 MB
#define WS_WRB   225845248ull   // packed rb conv w bf16 [4][27][256][256]
#define WS_W1P   240001024ull   // w1 packed bf16 [8][256][256]
#define WS_W2P   241049600ull
#define WS_C8P   242098176ull
#define WS_SF    242753536ull   // bn scale/shift [2][256]
#define WS_AUXP  242755584ull   // aux partials [128][16]

__device__ __forceinline__ u16 f2bf(float f) {
  u32 x = __float_as_uint(f);
  u32 r = x + 0x7fffu + ((x >> 16) & 1u);
  return (u16)(r >> 16);
}

// ---------------- transpose x [C][T] -> x_t fp32 + tokens bf16 [T][C] ----------------
__global__ void trans_in_k(const float* __restrict__ x, float* __restrict__ xt,
                           u16* __restrict__ tok) {
  __shared__ float ld[64][65];
  int tt = blockIdx.x, cc = blockIdx.y, tid = threadIdx.x;
#pragma unroll
  for (int k = 0; k < 16; ++k) {
    int idx = tid + k * 256;
    int cl = idx >> 6, j = idx & 63;
    ld[cl][j] = x[(size_t)(cc * 64 + cl) * 32768 + tt * 64 + j];
  }
  __syncthreads();
#pragma unroll
  for (int k = 0; k < 16; ++k) {
    int idx = tid + k * 256;
    int tl = idx >> 6, cl = idx & 63;
    float v = ld[cl][tl];
    size_t o = (size_t)(tt * 64 + tl) * 256 + cc * 64 + cl;
    xt[o] = v;
    tok[o] = f2bf(v);
  }
}

// ---------------- pack resblock conv weights ----------------
__global__ void pack_rb_k(const float* __restrict__ w0, const float* __restrict__ w1,
                          const float* __restrict__ w2, const float* __restrict__ w3,
                          u16* __restrict__ out) {
  __shared__ float ld[6912];
  int conv = blockIdx.x >> 8, blk = blockIdx.x & 255, tid = threadIdx.x;
  const float* src = conv == 0 ? w0 : conv == 1 ? w1 : conv == 2 ? w2 : w3;
  size_t base = (size_t)blk * 256 * 27;
#pragma unroll
  for (int k = 0; k < 27; ++k) ld[tid + k * 256] = src[base + tid + k * 256];
  __syncthreads();
  u16* dst = out + (size_t)conv * 27 * 65536;
  int n = blk * 256 + tid;
#pragma unroll
  for (int tap = 0; tap < 27; ++tap)
    dst[(size_t)tap * 65536 + n] = f2bf(ld[tid * 27 + tap]);
}

// ---------------- transpose-pack w1/w2 256x256 matrices to [N][K] bf16 ----------------
__global__ void pack_tr_k(const float* __restrict__ w1, const float* __restrict__ w2,
                          u16* __restrict__ w1p, u16* __restrict__ w2p) {
  __shared__ float ld[64][65];
  int m = blockIdx.y, tile = blockIdx.x, tid = threadIdx.x;
  const float* src = (m < 8) ? (w1 + (size_t)m * 65536) : (w2 + (size_t)(m - 8) * 65536);
  u16* dst = (m < 8) ? (w1p + (size_t)m * 65536) : (w2p + (size_t)(m - 8) * 65536);
  int r0 = (tile >> 2) * 64, c0 = (tile & 3) * 64;
#pragma unroll
  for (int k = 0; k < 16; ++k) {
    int idx = tid + k * 256;
    int rr = idx >> 6, cc = idx & 63;
    ld[rr][cc] = src[(size_t)(r0 + rr) * 256 + c0 + cc];
  }
  __syncthreads();
#pragma unroll
  for (int k = 0; k < 16; ++k) {
    int idx = tid + k * 256;
    int cc = idx >> 6, rr = idx & 63;
    dst[(size_t)(c0 + cc) * 256 + r0 + rr] = f2bf(ld[rr][cc]);
  }
}

__global__ void cvt_k(const float* __restrict__ in, u16* __restrict__ out, int n) {
  int i = blockIdx.x * 256 + threadIdx.x;
  if (i < n) out[i] = f2bf(in[i]);
}

// ---------------- zero halo rows of both padded buffers ----------------
__global__ void halo_k(u16* __restrict__ P1, u16* __restrict__ P2) {
  int gid = blockIdx.x * 256 + threadIdx.x;
  int r = gid >> 5, o = (gid & 31) << 3;
  if (r >= 39304) return;
  int d = r / 1156, rem = r - d * 1156, h = rem / 34, w = rem - h * 34;
  if (d >= 1 && d <= 32 && h >= 1 && h <= 32 && w >= 1 && w <= 32) return;
  uint4 z = {0u, 0u, 0u, 0u};
  *(uint4*)(P1 + (size_t)r * 256 + o) = z;
  *(uint4*)(P2 + (size_t)r * 256 + o) = z;
}

// ---------------- gating: softmax + top2 + aux partials ----------------
__global__ void gate_k(const float* __restrict__ xt, const float* __restrict__ wg,
                       float* __restrict__ gates, float* __restrict__ auxp) {
  __shared__ float wgs[2048];
  __shared__ float ax[4][16];
  int tid = threadIdx.x;
#pragma unroll
  for (int k = 0; k < 8; ++k) wgs[tid + k * 256] = wg[tid + k * 256];
  __syncthreads();
  int t = blockIdx.x * 256 + tid;
  int lane = tid & 63, wv = tid >> 6;
  float l[8] = {0, 0, 0, 0, 0, 0, 0, 0};
  const float* xr = xt + (size_t)t * 256;
  for (int c = 0; c < 256; c += 4) {
    float4 xv = *(const float4*)(xr + c);
#pragma unroll
    for (int e = 0; e < 8; ++e)
      l[e] += xv.x * wgs[c * 8 + e] + xv.y * wgs[(c + 1) * 8 + e] +
              xv.z * wgs[(c + 2) * 8 + e] + xv.w * wgs[(c + 3) * 8 + e];
  }
  float mx = l[0];
#pragma unroll
  for (int e = 1; e < 8; ++e) mx = fmaxf(mx, l[e]);
  float p[8], sum = 0.f;
#pragma unroll
  for (int e = 0; e < 8; ++e) { p[e] = __expf(l[e] - mx); sum += p[e]; }
  float inv = 1.0f / sum;
#pragma unroll
  for (int e = 0; e < 8; ++e) p[e] *= inv;
  int i0 = 0; float v0 = p[0];
#pragma unroll
  for (int e = 1; e < 8; ++e) if (p[e] > v0) { v0 = p[e]; i0 = e; }
  int i1 = -1; float v1 = -1.0f;
#pragma unroll
  for (int e = 0; e < 8; ++e) if (e != i0 && p[e] > v1) { v1 = p[e]; i1 = e; }
  float wsum = v0 + v1;
  float g0 = v0 / wsum, g1 = v1 / wsum;
  float* gr = gates + (size_t)t * 8;
#pragma unroll
  for (int e = 0; e < 8; ++e) gr[e] = (e == i0) ? g0 : (e == i1) ? g1 : 0.0f;
#pragma unroll
  for (int e = 0; e < 8; ++e) {
    float ps = p[e];
    float cn = (e == i0 || e == i1) ? 1.0f : 0.0f;
    for (int o = 32; o; o >>= 1) { ps += __shfl_down(ps, o); cn += __shfl_down(cn, o); }
    if (lane == 0) { ax[wv][e] = ps; ax[wv][8 + e] = cn; }
  }
  __syncthreads();
  if (tid < 16)
    auxp[blockIdx.x * 16 + tid] = ax[0][tid] + ax[1][tid] + ax[2][tid] + ax[3][tid];
}

__global__ void aux_k(const float* __restrict__ auxp, float* __restrict__ out) {
  __shared__ float s[16];
  int i = threadIdx.x;
  if (i < 16) {
    float a = 0;
    for (int b = 0; b < 128; ++b) a += auxp[b * 16 + i];
    s[i] = a;
  }
  __syncthreads();
  if (i == 0) {
    float r = 0;
    for (int e = 0; e < 8; ++e)
      r += (s[8 + e] * (1.0f / 32768.0f)) * (s[e] * (1.0f / 32768.0f));
    out[0] = r * 8.0f;
  }
}

// ---------------- fused MoE v2: 64-token tiles, weights global->VGPR ----------------
// 512 thr = 8 waves of (64t x 32c). LDS: tok 32KB | Hs 32KB. 2 barriers/expert.
__global__ __launch_bounds__(512, 4) void moe_k(
    const u16* __restrict__ tok, const u16* __restrict__ w1p,
    const u16* __restrict__ w2p, const float* __restrict__ b1,
    const float* __restrict__ b2, const float* __restrict__ gates,
    float* __restrict__ moe) {
  __shared__ __attribute__((aligned(16))) unsigned char smem[65536];
  const int tid = threadIdx.x;
  const int ttile = blockIdx.x;  // 512 tiles of 64 tokens
  const int lane = tid & 63;
  const int wv = tid >> 6;
  const int wc = wv * 32;
  const int fq = lane >> 4, fr = lane & 15;

  // stage tok [64][256] bf16: 2048 16B-chunks; LDS[r][ck] = G[r][ck^(r&7)] per 128B block
#pragma unroll
  for (int it = 0; it < 4; ++it) {
    int s = tid + it * 512;
    int r = s >> 5, seg = s & 31;
    int cole = ((seg >> 3) << 6) + (((seg & 7) ^ (r & 7)) << 3);
    __builtin_amdgcn_global_load_lds(
        (const __attribute__((address_space(1))) u32*)(tok + (size_t)(ttile * 64 + r) * 256 + cole),
        (__attribute__((address_space(3))) u32*)(smem + s * 16), 16, 0, 0);
  }
  __syncthreads();

  f32x4 macc[4][2];
#pragma unroll
  for (int m = 0; m < 4; ++m)
#pragma unroll
    for (int n = 0; n < 2; ++n) macc[m][n] = (f32x4){0.f, 0.f, 0.f, 0.f};

#pragma unroll 1
  for (int e = 0; e < 8; ++e) {
    const u16* w1e = w1p + e * 65536;
    const u16* w2e = w2p + e * 65536;

    // ---- GEMM1: h = gelu(tok @ w1e^T + b1); A from LDS, B from global ----
    f32x4 acc[4][2];
#pragma unroll
    for (int m = 0; m < 4; ++m)
#pragma unroll
      for (int n = 0; n < 2; ++n) acc[m][n] = (f32x4){0.f, 0.f, 0.f, 0.f};
#pragma unroll
    for (int kc = 0; kc < 4; ++kc) {
#pragma unroll
      for (int khf = 0; khf < 2; ++khf) {
        short8 bb[2], af[4];
#pragma unroll
        for (int n = 0; n < 2; ++n)
          bb[n] = *(const short8*)(w1e + (wc + n * 16 + fr) * 256 + kc * 64 + khf * 32 + fq * 8);
#pragma unroll
        for (int m = 0; m < 4; ++m) {
          int r = m * 16 + fr;
          int off = (kc * 128 + khf * 64 + fq * 16) ^ ((r & 7) << 4);
          af[m] = *(const short8*)(smem + r * 512 + off);
        }
#pragma unroll
        for (int m = 0; m < 4; ++m)
#pragma unroll
          for (int n = 0; n < 2; ++n)
            acc[m][n] = __builtin_amdgcn_mfma_f32_16x16x32_bf16(af[m], bb[n], acc[m][n], 0, 0, 0);
      }
    }

    // epilogue: bias+gelu, lane-pair merge to dwords, swizzled Hs write
    float bs1[2];
#pragma unroll
    for (int n = 0; n < 2; ++n) bs1[n] = b1[e * 256 + wc + n * 16 + fr];
    int pr = fr & 1;
#pragma unroll
    for (int m = 0; m < 4; ++m) {
#pragma unroll
      for (int n = 0; n < 2; ++n) {
        float g[4];
#pragma unroll
        for (int j = 0; j < 4; ++j) {
          float v = acc[m][n][j] + bs1[n];
          float u = 1.5957691216057308f * (v + 0.044715f * v * v * v);
          g[j] = v / (1.0f + __expf(-u));
        }
        u32 u0 = (u32)f2bf(g[0]) | ((u32)f2bf(g[1]) << 16);
        u32 u1 = (u32)f2bf(g[2]) | ((u32)f2bf(g[3]) << 16);
        u32 p0 = __shfl_xor((int)u0, 1);
        u32 p1 = __shfl_xor((int)u1, 1);
        u32 wA = pr ? ((p1 & 0xffffu) | (u1 << 16)) : ((u0 & 0xffffu) | (p0 << 16));
        u32 wB = pr ? ((p1 >> 16) | (u1 & 0xffff0000u)) : ((u0 >> 16) | (p0 & 0xffff0000u));
        int rA = m * 16 + fq * 4 + (pr << 1);
        int rB = rA + 1;
        int c = wc + n * 16 + fr;
        int cb = (c & ~1) * 2;
        *(u32*)(smem + 32768 + rA * 512 + (cb ^ ((rA & 7) << 4))) = wA;
        *(u32*)(smem + 32768 + rB * 512 + (cb ^ ((rB & 7) << 4))) = wB;
      }
    }
    __syncthreads();  // Hs visible to all waves

    // ---- GEMM2: eo = h @ w2e^T + b2 ----
    f32x4 acc2[4][2];
#pragma unroll
    for (int m = 0; m < 4; ++m)
#pragma unroll
      for (int n = 0; n < 2; ++n) acc2[m][n] = (f32x4){0.f, 0.f, 0.f, 0.f};
#pragma unroll
    for (int kc = 0; kc < 4; ++kc) {
#pragma unroll
      for (int khf = 0; khf < 2; ++khf) {
        short8 bb[2], af[4];
#pragma unroll
        for (int n = 0; n < 2; ++n)
          bb[n] = *(const short8*)(w2e + (wc + n * 16 + fr) * 256 + kc * 64 + khf * 32 + fq * 8);
#pragma unroll
        for (int m = 0; m < 4; ++m) {
          int r = m * 16 + fr;
          int off = (kc * 128 + khf * 64 + fq * 16) ^ ((r & 7) << 4);
          af[m] = *(const short8*)(smem + 32768 + r * 512 + off);
        }
#pragma unroll
        for (int m = 0; m < 4; ++m)
#pragma unroll
          for (int n = 0; n < 2; ++n)
            acc2[m][n] = __builtin_amdgcn_mfma_f32_16x16x32_bf16(af[m], bb[n], acc2[m][n], 0, 0, 0);
      }
    }
    __syncthreads();  // safe to overwrite Hs next expert

    float bs2[2];
#pragma unroll
    for (int n = 0; n < 2; ++n) bs2[n] = b2[e * 256 + wc + n * 16 + fr];
#pragma unroll
    for (int m = 0; m < 4; ++m)
#pragma unroll
      for (int j = 0; j < 4; ++j) {
        int t = ttile * 64 + m * 16 + fq * 4 + j;
        float g = gates[(size_t)t * 8 + e];
#pragma unroll
        for (int n = 0; n < 2; ++n)
          macc[m][n][j] += g * (acc2[m][n][j] + bs2[n]);
      }
  }

#pragma unroll
  for (int m = 0; m < 4; ++m)
#pragma unroll
    for (int j = 0; j < 4; ++j) {
      int t = ttile * 64 + m * 16 + fq * 4 + j;
      float* mr = moe + (size_t)t * 256 + wc;
#pragma unroll
      for (int n = 0; n < 2; ++n) mr[n * 16 + fr] = macc[m][n][j];
    }
}

// ---------------- conv3x3x3: halo-slab in LDS, weights global->VGPR ----------------
// block 256 thr (2x2 waves), out tile 128t x 128c. Slab per kc: [3][6][34] rows x 64ch = 78336B.
// 27 taps x 32 MFMA per stage-barrier pair. Fused BN partial sums.
__global__ __launch_bounds__(256, 2) void conv_k(
    const u16* __restrict__ P, const u16* __restrict__ W,
    const float* __restrict__ bias, float* __restrict__ y,
    float* __restrict__ part) {
  __shared__ __attribute__((aligned(16))) unsigned char smem[78336];
  const int tid = threadIdx.x;
  const int ttile = blockIdx.x;  // 256: dd = ttile>>3, h0 = (ttile&7)*4
  const int ctile = blockIdx.y;  // 2
  const int lane = tid & 63, wv = tid >> 6;
  const int wr = (wv >> 1) * 64, wc = (wv & 1) * 64;
  const int fq = lane >> 4, fr = lane & 15;
  const int dd = ttile >> 3, h0 = (ttile & 7) * 4;

  // precompute slab staging source offsets (global elements, sans kc)
  int goff[20];
#pragma unroll
  for (int it = 0; it < 20; ++it) {
    int s = tid + it * 256;
    int sr = s >> 3, ck = s & 7;
    int dl = sr / 204, r2 = sr - dl * 204;
    int hh = r2 / 34, ww = r2 - hh * 34;
    int prow = (dd + dl) * 1156 + (h0 + hh) * 34 + ww;
    goff[it] = prow * 256 + ((ck ^ (sr & 7)) << 3);
  }

  // per-m token spatial coords
  int hl[4], wl[4];
#pragma unroll
  for (int m = 0; m < 4; ++m) {
    int t = wr + m * 16 + fr;
    hl[m] = t >> 5;
    wl[m] = t & 31;
  }
  // weight row base pointers
  const u16* wrow[4];
#pragma unroll
  for (int n = 0; n < 4; ++n)
    wrow[n] = W + (size_t)(ctile * 128 + wc + n * 16 + fr) * 256;

  f32x4 acc[4][4];
#pragma unroll
  for (int m = 0; m < 4; ++m)
#pragma unroll
    for (int n = 0; n < 4; ++n) acc[m][n] = (f32x4){0.f, 0.f, 0.f, 0.f};

#pragma unroll 1
  for (int kc = 0; kc < 4; ++kc) {
#pragma unroll
    for (int it = 0; it < 20; ++it) {
      int s = tid + it * 256;
      if (s < 4896)
        __builtin_amdgcn_global_load_lds(
            (const __attribute__((address_space(1))) u32*)(P + goff[it] + kc * 64),
            (__attribute__((address_space(3))) u32*)(smem + s * 16), 16, 0, 0);
    }
    __syncthreads();

    int kd = 0, kh = 0, kw = 0;
#pragma unroll 1
    for (int tap = 0; tap < 27; ++tap) {
      const u16* Wt = W + tap * 65536 - (W - (const u16*)0) * 0;  // keep simple
      int srb[4];
#pragma unroll
      for (int m = 0; m < 4; ++m)
        srb[m] = (kd * 6 + hl[m] + kh) * 34 + wl[m] + kw;
#pragma unroll
      for (int khf = 0; khf < 2; ++khf) {
        short8 af[4], bb[4];
#pragma unroll
        for (int m = 0; m < 4; ++m) {
          int sr = srb[m];
          int off = ((khf * 4 + fq) ^ (sr & 7)) << 4;
          af[m] = *(const short8*)(smem + sr * 128 + off);
        }
#pragma unroll
        for (int n = 0; n < 4; ++n)
          bb[n] = *(const short8*)(wrow[n] + tap * 65536 + kc * 64 + khf * 32 + fq * 8);
#pragma unroll
        for (int m = 0; m < 4; ++m)
#pragma unroll
          for (int n = 0; n < 4; ++n)
            acc[m][n] = __builtin_amdgcn_mfma_f32_16x16x32_bf16(af[m], bb[n], acc[m][n], 0, 0, 0);
      }
      if (++kw == 3) { kw = 0; if (++kh == 3) { kh = 0; ++kd; } }
    }
    __syncthreads();
  }

  float bs[4];
#pragma unroll
  for (int n = 0; n < 4; ++n) bs[n] = bias[ctile * 128 + wc + n * 16 + fr];

  float sn[4] = {0, 0, 0, 0}, qn[4] = {0, 0, 0, 0};
#pragma unroll
  for (int m = 0; m < 4; ++m) {
#pragma unroll
    for (int j = 0; j < 4; ++j) {
      int t = ttile * 128 + wr + m * 16 + fq * 4 + j;
      float* yr = y + (size_t)t * 256 + ctile * 128 + wc;
#pragma unroll
      for (int n = 0; n < 4; ++n) {
        float v = acc[m][n][j] + bs[n];
        yr[n * 16 + fr] = v;
        sn[n] += v;
        qn[n] += v * v;
      }
    }
  }
  // reduce over fq groups (lane bits 4,5) -> column partials over this wave's 64 rows
#pragma unroll
  for (int n = 0; n < 4; ++n) {
    float s = sn[n], q = qn[n];
    s += __shfl_xor(s, 16); s += __shfl_xor(s, 32);
    q += __shfl_xor(q, 16); q += __shfl_xor(q, 32);
    if (lane < 16) {
      int pi = (ttile * 2 + (wv >> 1)) * 256 + ctile * 128 + wc + n * 16 + fr;
      part[pi] = s;
      part[131072 + pi] = q;
    }
  }
}

// ---------------- BN stats reduce: part [2][512][256] -> scale/shift ----------------
__global__ void stats2_k(const float* __restrict__ part, const float* __restrict__ g,
                         const float* __restrict__ be, float* __restrict__ sf) {
  __shared__ float sred[4][256], qred[4][256];
  int tid = threadIdx.x;
  int c = tid & 255, qd = tid >> 8;
  float s = 0, q = 0;
  for (int b = qd * 128; b < qd * 128 + 128; ++b) {
    s += part[b * 256 + c];
    q += part[131072 + b * 256 + c];
  }
  sred[qd][c] = s;
  qred[qd][c] = q;
  __syncthreads();
  if (qd == 0) {
    s = sred[0][c] + sred[1][c] + sred[2][c] + sred[3][c];
    q = qred[0][c] + qred[1][c] + qred[2][c] + qred[3][c];
    float mean = s * (1.0f / 32768.0f);
    float var = q * (1.0f / 32768.0f) - mean * mean;
    float a = g[c] * rsqrtf(var + 1e-5f);
    sf[c] = a;
    sf[256 + c] = be[c] - mean * a;
  }
}

// ---------------- BN apply (+leaky, +skip) ----------------
template <int V>
__global__ void bn_k(const float* __restrict__ y, const float* __restrict__ sf,
                     const float* __restrict__ skip, u16* __restrict__ pad,
                     float* __restrict__ f32o, u16* __restrict__ bfo) {
  int gid = blockIdx.x * 256 + threadIdx.x;
  int t = gid >> 5, c0 = (gid & 31) << 3;
  size_t base = (size_t)t * 256 + c0;
  float v[8];
  const float4* yp = (const float4*)(y + base);
  float4 y0 = yp[0], y1 = yp[1];
  const float4* ap = (const float4*)(sf + c0);
  float4 a0 = ap[0], a1 = ap[1];
  const float4* shp = (const float4*)(sf + 256 + c0);
  float4 s0 = shp[0], s1 = shp[1];
  v[0] = a0.x * y0.x + s0.x; v[1] = a0.y * y0.y + s0.y;
  v[2] = a0.z * y0.z + s0.z; v[3] = a0.w * y0.w + s0.w;
  v[4] = a1.x * y1.x + s1.x; v[5] = a1.y * y1.y + s1.y;
  v[6] = a1.z * y1.z + s1.z; v[7] = a1.w * y1.w + s1.w;
  if (V >= 1) {
    const float4* kp = (const float4*)(skip + base);
    float4 k0 = kp[0], k1 = kp[1];
    v[0] += k0.x; v[1] += k0.y; v[2] += k0.z; v[3] += k0.w;
    v[4] += k1.x; v[5] += k1.y; v[6] += k1.z; v[7] += k1.w;
  }
#pragma unroll
  for (int i = 0; i < 8; ++i) v[i] = v[i] > 0.0f ? v[i] : 0.01f * v[i];
  if (V <= 1) {
    int d = t >> 10, h = (t >> 5) & 31, w = t & 31;
    int prow = (d + 1) * 1156 + (h + 1) * 34 + (w + 1);
    uint4 pk;
    pk.x = (u32)f2bf(v[0]) | ((u32)f2bf(v[1]) << 16);
    pk.y = (u32)f2bf(v[2]) | ((u32)f2bf(v[3]) << 16);
    pk.z = (u32)f2bf(v[4]) | ((u32)f2bf(v[5]) << 16);
    pk.w = (u32)f2bf(v[6]) | ((u32)f2bf(v[7]) << 16);
    *(uint4*)(pad + (size_t)prow * 256 + c0) = pk;
  }
  if (V == 1) {
    float4 o0 = {v[0], v[1], v[2], v[3]}, o1 = {v[4], v[5], v[6], v[7]};
    float4* fp = (float4*)(f32o + base);
    fp[0] = o0; fp[1] = o1;
  }
  if (V == 2) {
    uint4 pk;
    pk.x = (u32)f2bf(v[0]) | ((u32)f2bf(v[1]) << 16);
    pk.y = (u32)f2bf(v[2]) | ((u32)f2bf(v[3]) << 16);
    pk.z = (u32)f2bf(v[4]) | ((u32)f2bf(v[5]) << 16);
    pk.w = (u32)f2bf(v[6]) | ((u32)f2bf(v[7]) << 16);
    *(uint4*)(bfo + base) = pk;
  }
}

// ---------------- xm = x + moe: writes xm_tc (in place), xm_ct, xm_pad ----------------
__global__ void xm_k(float* __restrict__ xt, const float* __restrict__ moe,
                     float* __restrict__ xmct, u16* __restrict__ pad) {
  __shared__ float ld[64][65];
  int tt = blockIdx.x, cc = blockIdx.y, tid = threadIdx.x;
#pragma unroll
  for (int k = 0; k < 16; ++k) {
    int idx = tid + k * 256;
    int tl = idx >> 6, cl = idx & 63;
    size_t o = (size_t)(tt * 64 + tl) * 256 + cc * 64 + cl;
    float v = xt[o] + moe[o];
    xt[o] = v;
    ld[tl][cl] = v;
    int t = tt * 64 + tl;
    int d = t >> 10, h = (t >> 5) & 31, w = t & 31;
    int prow = (d + 1) * 1156 + (h + 1) * 34 + (w + 1);
    pad[(size_t)prow * 256 + cc * 64 + cl] = f2bf(v);
  }
  __syncthreads();
#pragma unroll
  for (int k = 0; k < 16; ++k) {
    int idx = tid + k * 256;
    int cl = idx >> 6, tl = idx & 63;
    xmct[(size_t)(cc * 64 + cl) * 32768 + tt * 64 + tl] = ld[tl][cl];
  }
}

// ---------------- final 1x1 conv: out[oc][t] = acc + bias + xmct[oc][t] ----------------
__global__ __launch_bounds__(256, 2) void final_k(
    const u16* __restrict__ A, const u16* __restrict__ Bw,
    const float* __restrict__ bias, float* __restrict__ outF,
    const float* __restrict__ xmct) {
  __shared__ __attribute__((aligned(16))) unsigned char smem[32768];
  const int tid = threadIdx.x;
  const int ttile = blockIdx.x;
  const int ctile = blockIdx.y;
  const int lane = tid & 63;
  const int wv = tid >> 6;
  const int wr = (wv >> 1) << 6;
  const int wc = (wv & 1) << 6;
  const int fq = lane >> 4;
  const int fr = lane & 15;

  int aoff[4], boff[4];
#pragma unroll
  for (int it = 0; it < 4; ++it) {
    int s = tid + it * 256;
    int r = s >> 3;
    int lsg = (s & 7) ^ (r & 7);
    aoff[it] = (ttile * 128 + r) * 256 + lsg * 8;
    boff[it] = (ctile * 128 + r) * 256 + lsg * 8;
  }

  f32x4 acc[4][4];
#pragma unroll
  for (int m = 0; m < 4; ++m)
#pragma unroll
    for (int n = 0; n < 4; ++n) acc[m][n] = (f32x4){0.f, 0.f, 0.f, 0.f};

#pragma unroll 1
  for (int kc = 0; kc < 4; ++kc) {
    const u16* Ak = A + kc * 64;
    const u16* Bk = Bw + kc * 64;
#pragma unroll
    for (int it = 0; it < 4; ++it) {
      __builtin_amdgcn_global_load_lds(
          (const __attribute__((address_space(1))) u32*)(Ak + aoff[it]),
          (__attribute__((address_space(3))) u32*)(smem + (tid + it * 256) * 16),
          16, 0, 0);
      __builtin_amdgcn_global_load_lds(
          (const __attribute__((address_space(1))) u32*)(Bk + boff[it]),
          (__attribute__((address_space(3))) u32*)(smem + 16384 + (tid + it * 256) * 16),
          16, 0, 0);
    }
    __syncthreads();
#pragma unroll
    for (int khf = 0; khf < 2; ++khf) {
      short8 af[4], bb[4];
#pragma unroll
      for (int m = 0; m < 4; ++m) {
        int row = wr + m * 16 + fr;
        int p = (khf * 4 + fq) ^ (row & 7);
        af[m] = *(const short8*)(smem + row * 128 + p * 16);
      }
#pragma unroll
      for (int n = 0; n < 4; ++n) {
        int row = wc + n * 16 + fr;
        int p = (khf * 4 + fq) ^ (row & 7);
        bb[n] = *(const short8*)(smem + 16384 + row * 128 + p * 16);
      }
#pragma unroll
      for (int m = 0; m < 4; ++m)
#pragma unroll
        for (int n = 0; n < 4; ++n)
          acc[m][n] = __builtin_amdgcn_mfma_f32_16x16x32_bf16(af[m], bb[n], acc[m][n], 0, 0, 0);
    }
    __syncthreads();
  }

  float bs[4];
#pragma unroll
  for (int n = 0; n < 4; ++n) bs[n] = bias[ctile * 128 + wc + n * 16 + fr];

#pragma unroll
  for (int m = 0; m < 4; ++m) {
    int trow = ttile * 128 + wr + m * 16 + fq * 4;
#pragma unroll
    for (int n = 0; n < 4; ++n) {
      int oc = ctile * 128 + wc + n * 16 + fr;
      size_t o = (size_t)oc * 32768 + trow;
      float4 xv = *(const float4*)(xmct + o);
      float4 w;
      w.x = acc[m][n][0] + bs[n] + xv.x;
      w.y = acc[m][n][1] + bs[n] + xv.y;
      w.z = acc[m][n][2] + bs[n] + xv.z;
      w.w = acc[m][n][3] + bs[n] + xv.w;
      *(float4*)(outF + o) = w;
    }
  }
}

extern "C" void kernel_launch(void* const* d_in, const int* in_sizes, int n_in,
                              void* d_out, int out_size, void* d_ws, size_t ws_size,
                              hipStream_t stream) {
  (void)in_sizes; (void)n_in; (void)out_size; (void)ws_size;
  const float* x  = (const float*)d_in[0];
  const float* wg = (const float*)d_in[1];
  const float* w1 = (const float*)d_in[2];
  const float* b1 = (const float*)d_in[3];
  const float* w2 = (const float*)d_in[4];
  const float* b2 = (const float*)d_in[5];

  char* ws = (char*)d_ws;
  u16* tok    = (u16*)(ws + WS_TOK);
  float* xt   = (float*)(ws + WS_XT);
  float* xmct = (float*)(ws + WS_XMCT);
  float* gates= (float*)(ws + WS_GATES);
  float* part = (float*)(ws + WS_PART);
  float* moe  = (float*)(ws + WS_MOE);
  u16* P1     = (u16*)(ws + WS_P1);
  u16* P2     = (u16*)(ws + WS_P2);
  float* ybuf = (float*)(ws + WS_Y);
  u16* r2b    = (u16*)(ws + WS_R2);
  u16* wrb    = (u16*)(ws + WS_WRB);
  u16* w1p    = (u16*)(ws + WS_W1P);
  u16* w2p    = (u16*)(ws + WS_W2P);
  u16* c8p    = (u16*)(ws + WS_C8P);
  float* sf   = (float*)(ws + WS_SF);
  float* auxp = (float*)(ws + WS_AUXP);
  float* outp = (float*)d_out;

  halo_k<<<4913, 256, 0, stream>>>(P1, P2);
  trans_in_k<<<dim3(512, 4), 256, 0, stream>>>(x, xt, tok);
  pack_rb_k<<<1024, 256, 0, stream>>>((const float*)d_in[6], (const float*)d_in[10],
                                      (const float*)d_in[14], (const float*)d_in[18], wrb);
  pack_tr_k<<<dim3(16, 16), 256, 0, stream>>>(w1, w2, w1p, w2p);
  cvt_k<<<256, 256, 0, stream>>>((const float*)d_in[22], c8p, 65536);
  gate_k<<<128, 256, 0, stream>>>(xt, wg, gates, auxp);

  moe_k<<<512, 512, 0, stream>>>(tok, w1p, w2p, b1, b2, gates, moe);
  xm_k<<<dim3(512, 4), 256, 0, stream>>>(xt, moe, xmct, P1);

  // resblock 1
  conv_k<<<dim3(256, 2), 256, 0, stream>>>(P1, wrb + 0 * 1769472, (const float*)d_in[7],
                                           ybuf, part);
  stats2_k<<<1, 1024, 0, stream>>>(part, (const float*)d_in[8], (const float*)d_in[9], sf);
  bn_k<0><<<4096, 256, 0, stream>>>(ybuf, sf, nullptr, P2, nullptr, nullptr);
  conv_k<<<dim3(256, 2), 256, 0, stream>>>(P2, wrb + 1 * 1769472, (const float*)d_in[11],
                                           ybuf, part);
  stats2_k<<<1, 1024, 0, stream>>>(part, (const float*)d_in[12], (const float*)d_in[13], sf);
  bn_k<1><<<4096, 256, 0, stream>>>(ybuf, sf, xt, P1, xt, nullptr);

  // resblock 2
  conv_k<<<dim3(256, 2), 256, 0, stream>>>(P1, wrb + 2 * 1769472, (const float*)d_in[15],
                                           ybuf, part);
  stats2_k<<<1, 1024, 0, stream>>>(part, (const float*)d_in[16], (const float*)d_in[17], sf);
  bn_k<0><<<4096, 256, 0, stream>>>(ybuf, sf, nullptr, P2, nullptr, nullptr);
  conv_k<<<dim3(256, 2), 256, 0, stream>>>(P2, wrb + 3 * 1769472, (const float*)d_in[19],
                                           ybuf, part);
  stats2_k<<<1, 1024, 0, stream>>>(part, (const float*)d_in[20], (const float*)d_in[21], sf);
  bn_k<2><<<4096, 256, 0, stream>>>(ybuf, sf, xt, nullptr, nullptr, r2b);

  // final: out = xm + conv1x1(res)
  final_k<<<dim3(256, 2), 256, 0, stream>>>(r2b, c8p, (const float*)d_in[23], outp, xmct);
  aux_k<<<1, 64, 0, stream>>>(auxp, outp + 8388608);
}

// Round 4
// 778.153 us; speedup vs baseline: 1.4862x; 1.4862x over previous
//
#include <hip/hip_runtime.h>
#include <stdint.h>

typedef __attribute__((ext_vector_type(8))) short short8;
typedef __attribute__((ext_vector_type(4))) float f32x4;
typedef unsigned short u16;
typedef unsigned int u32;
typedef unsigned long long u64;

// ---------------- workspace layout (bytes) ----------------
#define WS_TOK   0ull           // tokens bf16 [32768][256]            16 MB
#define WS_XT    16777216ull    // x_t -> xm_tc -> r1 fp32 [T][C]      32 MB
#define WS_XMCT  50331648ull    // xm fp32 [C][T]                      32 MB
#define WS_GATES 83886080ull    // gates fp32 [T][8]                    1 MB
#define WS_PART  84934656ull    // bn partials [2][512][256] fp32       1 MB
#define WS_MOE   101711872ull   // moe fp32 [T][256]                   32 MB
#define WS_P1    135266304ull   // padded bf16 [34^3][256]             19.2MB
#define WS_P2    155389952ull
#define WS_Y     175513600ull   // conv out fp32 [T][256]              32 MB
#define WS_R2    209068032ull   // r2 bf16 [T][256]                    16 MB
#define WS_WRB   225845248ull   // packed rb conv w bf16 [4][27][256][256]
#define WS_W1P   240001024ull   // w1 packed bf16 [8][256][256]
#define WS_W2P   241049600ull
#define WS_C8P   242098176ull
#define WS_SF    242753536ull   // bn scale/shift [2][256]
#define WS_AUXP  242755584ull   // aux partials [128][16]

__device__ __forceinline__ u16 f2bf(float f) {
  u32 x = __float_as_uint(f);
  u32 r = x + 0x7fffu + ((x >> 16) & 1u);
  return (u16)(r >> 16);
}

// ---------------- transpose x [C][T] -> x_t fp32 + tokens bf16 [T][C] ----------------
__global__ void trans_in_k(const float* __restrict__ x, float* __restrict__ xt,
                           u16* __restrict__ tok) {
  __shared__ float ld[64][65];
  int tt = blockIdx.x, cc = blockIdx.y, tid = threadIdx.x;
#pragma unroll
  for (int k = 0; k < 16; ++k) {
    int idx = tid + k * 256;
    int cl = idx >> 6, j = idx & 63;
    ld[cl][j] = x[(size_t)(cc * 64 + cl) * 32768 + tt * 64 + j];
  }
  __syncthreads();
#pragma unroll
  for (int k = 0; k < 16; ++k) {
    int idx = tid + k * 256;
    int tl = idx >> 6, cl = idx & 63;
    float v = ld[cl][tl];
    size_t o = (size_t)(tt * 64 + tl) * 256 + cc * 64 + cl;
    xt[o] = v;
    tok[o] = f2bf(v);
  }
}

// ---------------- pack resblock conv weights ----------------
__global__ void pack_rb_k(const float* __restrict__ w0, const float* __restrict__ w1,
                          const float* __restrict__ w2, const float* __restrict__ w3,
                          u16* __restrict__ out) {
  __shared__ float ld[6912];
  int conv = blockIdx.x >> 8, blk = blockIdx.x & 255, tid = threadIdx.x;
  const float* src = conv == 0 ? w0 : conv == 1 ? w1 : conv == 2 ? w2 : w3;
  size_t base = (size_t)blk * 256 * 27;
#pragma unroll
  for (int k = 0; k < 27; ++k) ld[tid + k * 256] = src[base + tid + k * 256];
  __syncthreads();
  u16* dst = out + (size_t)conv * 27 * 65536;
  int n = blk * 256 + tid;
#pragma unroll
  for (int tap = 0; tap < 27; ++tap)
    dst[(size_t)tap * 65536 + n] = f2bf(ld[tid * 27 + tap]);
}

// ---------------- transpose-pack w1/w2 256x256 matrices to [N][K] bf16 ----------------
__global__ void pack_tr_k(const float* __restrict__ w1, const float* __restrict__ w2,
                          u16* __restrict__ w1p, u16* __restrict__ w2p) {
  __shared__ float ld[64][65];
  int m = blockIdx.y, tile = blockIdx.x, tid = threadIdx.x;
  const float* src = (m < 8) ? (w1 + (size_t)m * 65536) : (w2 + (size_t)(m - 8) * 65536);
  u16* dst = (m < 8) ? (w1p + (size_t)m * 65536) : (w2p + (size_t)(m - 8) * 65536);
  int r0 = (tile >> 2) * 64, c0 = (tile & 3) * 64;
#pragma unroll
  for (int k = 0; k < 16; ++k) {
    int idx = tid + k * 256;
    int rr = idx >> 6, cc = idx & 63;
    ld[rr][cc] = src[(size_t)(r0 + rr) * 256 + c0 + cc];
  }
  __syncthreads();
#pragma unroll
  for (int k = 0; k < 16; ++k) {
    int idx = tid + k * 256;
    int cc = idx >> 6, rr = idx & 63;
    dst[(size_t)(c0 + cc) * 256 + r0 + rr] = f2bf(ld[rr][cc]);
  }
}

__global__ void cvt_k(const float* __restrict__ in, u16* __restrict__ out, int n) {
  int i = blockIdx.x * 256 + threadIdx.x;
  if (i < n) out[i] = f2bf(in[i]);
}

// ---------------- zero halo rows of both padded buffers ----------------
__global__ void halo_k(u16* __restrict__ P1, u16* __restrict__ P2) {
  int gid = blockIdx.x * 256 + threadIdx.x;
  int r = gid >> 5, o = (gid & 31) << 3;
  if (r >= 39304) return;
  int d = r / 1156, rem = r - d * 1156, h = rem / 34, w = rem - h * 34;
  if (d >= 1 && d <= 32 && h >= 1 && h <= 32 && w >= 1 && w <= 32) return;
  uint4 z = {0u, 0u, 0u, 0u};
  *(uint4*)(P1 + (size_t)r * 256 + o) = z;
  *(uint4*)(P2 + (size_t)r * 256 + o) = z;
}

// ---------------- gating: softmax + top2 + aux partials ----------------
__global__ void gate_k(const float* __restrict__ xt, const float* __restrict__ wg,
                       float* __restrict__ gates, float* __restrict__ auxp) {
  __shared__ float wgs[2048];
  __shared__ float ax[4][16];
  int tid = threadIdx.x;
#pragma unroll
  for (int k = 0; k < 8; ++k) wgs[tid + k * 256] = wg[tid + k * 256];
  __syncthreads();
  int t = blockIdx.x * 256 + tid;
  int lane = tid & 63, wv = tid >> 6;
  float l[8] = {0, 0, 0, 0, 0, 0, 0, 0};
  const float* xr = xt + (size_t)t * 256;
  for (int c = 0; c < 256; c += 4) {
    float4 xv = *(const float4*)(xr + c);
#pragma unroll
    for (int e = 0; e < 8; ++e)
      l[e] += xv.x * wgs[c * 8 + e] + xv.y * wgs[(c + 1) * 8 + e] +
              xv.z * wgs[(c + 2) * 8 + e] + xv.w * wgs[(c + 3) * 8 + e];
  }
  float mx = l[0];
#pragma unroll
  for (int e = 1; e < 8; ++e) mx = fmaxf(mx, l[e]);
  float p[8], sum = 0.f;
#pragma unroll
  for (int e = 0; e < 8; ++e) { p[e] = __expf(l[e] - mx); sum += p[e]; }
  float inv = 1.0f / sum;
#pragma unroll
  for (int e = 0; e < 8; ++e) p[e] *= inv;
  int i0 = 0; float v0 = p[0];
#pragma unroll
  for (int e = 1; e < 8; ++e) if (p[e] > v0) { v0 = p[e]; i0 = e; }
  int i1 = -1; float v1 = -1.0f;
#pragma unroll
  for (int e = 0; e < 8; ++e) if (e != i0 && p[e] > v1) { v1 = p[e]; i1 = e; }
  float wsum = v0 + v1;
  float g0 = v0 / wsum, g1 = v1 / wsum;
  float* gr = gates + (size_t)t * 8;
#pragma unroll
  for (int e = 0; e < 8; ++e) gr[e] = (e == i0) ? g0 : (e == i1) ? g1 : 0.0f;
#pragma unroll
  for (int e = 0; e < 8; ++e) {
    float ps = p[e];
    float cn = (e == i0 || e == i1) ? 1.0f : 0.0f;
    for (int o = 32; o; o >>= 1) { ps += __shfl_down(ps, o); cn += __shfl_down(cn, o); }
    if (lane == 0) { ax[wv][e] = ps; ax[wv][8 + e] = cn; }
  }
  __syncthreads();
  if (tid < 16)
    auxp[blockIdx.x * 16 + tid] = ax[0][tid] + ax[1][tid] + ax[2][tid] + ax[3][tid];
}

__global__ void aux_k(const float* __restrict__ auxp, float* __restrict__ out) {
  __shared__ float s[16];
  int i = threadIdx.x;
  if (i < 16) {
    float a = 0;
    for (int b = 0; b < 128; ++b) a += auxp[b * 16 + i];
    s[i] = a;
  }
  __syncthreads();
  if (i == 0) {
    float r = 0;
    for (int e = 0; e < 8; ++e)
      r += (s[8 + e] * (1.0f / 32768.0f)) * (s[e] * (1.0f / 32768.0f));
    out[0] = r * 8.0f;
  }
}

// ---------------- fused MoE: round-2 structure + swapped GEMM1 / b64 Hs writes ----
// 512 thr, tile = 128 tokens x 256 cols. LDS: tok 64KB | Bs 32KB | Hs 64KB.
// GEMM1 computes h^T-fragments (operands swapped) so each thread owns 4
// consecutive k of h -> 16x ds_write_b64 with XOR((t&7)<<4) swizzle.
__global__ __launch_bounds__(512, 2) void moe_k(
    const u16* __restrict__ tok, const u16* __restrict__ w1p,
    const u16* __restrict__ w2p, const float* __restrict__ b1,
    const float* __restrict__ b2, const float* __restrict__ gates,
    float* __restrict__ moe) {
  __shared__ __attribute__((aligned(16))) unsigned char smem[163840];
  const int tid = threadIdx.x;
  const int ttile = blockIdx.x;  // 256 tiles of 128 tokens
  const int lane = tid & 63;
  const int wv = tid >> 6;
  const int wr = (wv >> 2) * 64;  // t-slice
  const int wc = (wv & 3) * 64;   // c-slice
  const int fq = lane >> 4, fr = lane & 15;

  // stage tok [128][256] once (seg-swizzled source, linear LDS dest)
#pragma unroll
  for (int it = 0; it < 8; ++it) {
    int s = tid + it * 512;
    int r = s >> 5, seg = s & 31;
    int cole = ((seg >> 3) << 6) + (((seg & 7) ^ (r & 7)) << 3);
    __builtin_amdgcn_global_load_lds(
        (const __attribute__((address_space(1))) u32*)(tok + (size_t)(ttile * 128 + r) * 256 + cole),
        (__attribute__((address_space(3))) u32*)(smem + s * 16), 16, 0, 0);
  }

  f32x4 macc[4][4];
#pragma unroll
  for (int m = 0; m < 4; ++m)
#pragma unroll
    for (int n = 0; n < 4; ++n) macc[m][n] = (f32x4){0.f, 0.f, 0.f, 0.f};

#pragma unroll 1
  for (int e = 0; e < 8; ++e) {
    const u16* w1e = w1p + e * 65536;
    const u16* w2e = w2p + e * 65536;

    // ---- GEMM1 (swapped): acc1[mc][nt] = w1-rows x tok-rows -> h^T frags ----
    f32x4 acc1[4][4];
#pragma unroll
    for (int mc = 0; mc < 4; ++mc)
#pragma unroll
      for (int nt = 0; nt < 4; ++nt) acc1[mc][nt] = (f32x4){0.f, 0.f, 0.f, 0.f};

#pragma unroll 1
    for (int kc = 0; kc < 4; ++kc) {
#pragma unroll
      for (int it = 0; it < 4; ++it) {
        int s = tid + it * 512;
        int r = s >> 3;
        int sub = (s & 7) ^ (r & 7);
        __builtin_amdgcn_global_load_lds(
            (const __attribute__((address_space(1))) u32*)(w1e + (size_t)r * 256 + kc * 64 + sub * 8),
            (__attribute__((address_space(3))) u32*)(smem + 65536 + s * 16), 16, 0, 0);
      }
      __syncthreads();
#pragma unroll
      for (int khf = 0; khf < 2; ++khf) {
        short8 af1[4], bt[4];
#pragma unroll
        for (int mc = 0; mc < 4; ++mc) {
          int row = wc + mc * 16 + fr;
          int p = (khf * 4 + fq) ^ (row & 7);
          af1[mc] = *(const short8*)(smem + 65536 + row * 128 + p * 16);
        }
#pragma unroll
        for (int nt = 0; nt < 4; ++nt) {
          int row = wr + nt * 16 + fr;
          int p = (khf * 4 + fq) ^ (row & 7);
          bt[nt] = *(const short8*)(smem + row * 512 + kc * 128 + p * 16);
        }
#pragma unroll
        for (int mc = 0; mc < 4; ++mc)
#pragma unroll
          for (int nt = 0; nt < 4; ++nt)
            acc1[mc][nt] = __builtin_amdgcn_mfma_f32_16x16x32_bf16(af1[mc], bt[nt], acc1[mc][nt], 0, 0, 0);
      }
      __syncthreads();
    }

    // epilogue: h = gelu(acc1 + b1[c]); thread owns (c=k0..k0+3, t) -> b64 writes
#pragma unroll
    for (int mc = 0; mc < 4; ++mc) {
      int k0 = wc + mc * 16 + fq * 4;
      float4 bv = *(const float4*)(b1 + e * 256 + k0);
#pragma unroll
      for (int nt = 0; nt < 4; ++nt) {
        int t = wr + nt * 16 + fr;
        u64 pk = 0;
#pragma unroll
        for (int j = 0; j < 4; ++j) {
          float v = acc1[mc][nt][j] + ((const float*)&bv)[j];
          float u = 1.5957691216057308f * (v + 0.044715f * v * v * v);
          float g = v / (1.0f + __expf(-u));
          pk |= (u64)f2bf(g) << (16 * j);
        }
        *(u64*)(smem + 98304 + t * 512 + ((k0 * 2) ^ ((t & 7) << 4))) = pk;
      }
    }

    // ---- GEMM2: acc2[m][n] = h-rows x w2-rows ----
    f32x4 acc2[4][4];
#pragma unroll
    for (int m = 0; m < 4; ++m)
#pragma unroll
      for (int n = 0; n < 4; ++n) acc2[m][n] = (f32x4){0.f, 0.f, 0.f, 0.f};

#pragma unroll 1
    for (int kc = 0; kc < 4; ++kc) {
#pragma unroll
      for (int it = 0; it < 4; ++it) {
        int s = tid + it * 512;
        int r = s >> 3;
        int sub = (s & 7) ^ (r & 7);
        __builtin_amdgcn_global_load_lds(
            (const __attribute__((address_space(1))) u32*)(w2e + (size_t)r * 256 + kc * 64 + sub * 8),
            (__attribute__((address_space(3))) u32*)(smem + 65536 + s * 16), 16, 0, 0);
      }
      __syncthreads();  // publishes Hs (lgkm) + Bs2 (vm)
#pragma unroll
      for (int khf = 0; khf < 2; ++khf) {
        short8 af[4], bb[4];
#pragma unroll
        for (int m = 0; m < 4; ++m) {
          int row = wr + m * 16 + fr;
          int col = (kc * 128 + (khf * 4 + fq) * 16) ^ ((row & 7) << 4);
          af[m] = *(const short8*)(smem + 98304 + row * 512 + col);
        }
#pragma unroll
        for (int n = 0; n < 4; ++n) {
          int row = wc + n * 16 + fr;
          int p = (khf * 4 + fq) ^ (row & 7);
          bb[n] = *(const short8*)(smem + 65536 + row * 128 + p * 16);
        }
#pragma unroll
        for (int m = 0; m < 4; ++m)
#pragma unroll
          for (int n = 0; n < 4; ++n)
            acc2[m][n] = __builtin_amdgcn_mfma_f32_16x16x32_bf16(af[m], bb[n], acc2[m][n], 0, 0, 0);
      }
      __syncthreads();
    }

    float bs2[4];
#pragma unroll
    for (int n = 0; n < 4; ++n) bs2[n] = b2[e * 256 + wc + n * 16 + fr];
#pragma unroll
    for (int m = 0; m < 4; ++m)
#pragma unroll
      for (int j = 0; j < 4; ++j) {
        int t = ttile * 128 + wr + m * 16 + fq * 4 + j;
        float g = gates[(size_t)t * 8 + e];
#pragma unroll
        for (int n = 0; n < 4; ++n)
          macc[m][n][j] += g * (acc2[m][n][j] + bs2[n]);
      }
  }

#pragma unroll
  for (int m = 0; m < 4; ++m)
#pragma unroll
    for (int j = 0; j < 4; ++j) {
      int t = ttile * 128 + wr + m * 16 + fq * 4 + j;
      float* mr = moe + (size_t)t * 256 + wc;
#pragma unroll
      for (int n = 0; n < 4; ++n) mr[n * 16 + fr] = macc[m][n][j];
    }
}

// ---------------- unified MFMA GEMM (convs + final 1x1) ----------------
// MODE 0: conv3x3x3 from padded buffer, y = acc + bias -> fp32, + BN partials
// MODE 3: final 1x1 conv, out[oc][t] = acc + bias + xmct[oc][t]
template <int MODE>
__global__ __launch_bounds__(256, 2) void gemm_k(
    const u16* __restrict__ A, const u16* __restrict__ Bw,
    const float* __restrict__ bias, float* __restrict__ outF,
    const float* __restrict__ xmct, float* __restrict__ part) {
  __shared__ __attribute__((aligned(16))) unsigned char smem[32768];
  const int tid = threadIdx.x;
  const int ttile = blockIdx.x;
  const int ctile = blockIdx.y;
  const int lane = tid & 63;
  const int wv = tid >> 6;
  const int wr = (wv >> 1) << 6;
  const int wc = (wv & 1) << 6;
  const int fq = lane >> 4;
  const int fr = lane & 15;

  int aoff[4], boff[4];
#pragma unroll
  for (int it = 0; it < 4; ++it) {
    int s = tid + it * 256;
    int r = s >> 3;
    int lsg = (s & 7) ^ (r & 7);
    if (MODE == 0) {
      int dd = ttile >> 3;
      int h0 = (ttile & 7) << 2;
      int base = dd * 1156 + (h0 + (r >> 5)) * 34 + (r & 31);
      aoff[it] = base * 256 + lsg * 8;
    } else {
      aoff[it] = (ttile * 128 + r) * 256 + lsg * 8;
    }
    boff[it] = (ctile * 128 + r) * 256 + lsg * 8;
  }

  f32x4 acc[4][4];
#pragma unroll
  for (int m = 0; m < 4; ++m)
#pragma unroll
    for (int n = 0; n < 4; ++n) acc[m][n] = (f32x4){0.f, 0.f, 0.f, 0.f};

  const int nTap = (MODE == 0) ? 27 : 1;
#pragma unroll 1
  for (int tap = 0; tap < nTap; ++tap) {
    int atap = 0, btap = 0;
    if (MODE == 0) {
      atap = ((tap / 9) * 1156 + ((tap / 3) % 3) * 34 + (tap % 3)) * 256;
      btap = tap * 65536;
    }
#pragma unroll 1
    for (int kc = 0; kc < 4; ++kc) {
      const u16* Ak = A + atap + kc * 64;
      const u16* Bk = Bw + btap + kc * 64;
#pragma unroll
      for (int it = 0; it < 4; ++it) {
        __builtin_amdgcn_global_load_lds(
            (const __attribute__((address_space(1))) u32*)(Ak + aoff[it]),
            (__attribute__((address_space(3))) u32*)(smem + (tid + it * 256) * 16),
            16, 0, 0);
        __builtin_amdgcn_global_load_lds(
            (const __attribute__((address_space(1))) u32*)(Bk + boff[it]),
            (__attribute__((address_space(3))) u32*)(smem + 16384 + (tid + it * 256) * 16),
            16, 0, 0);
      }
      __syncthreads();
#pragma unroll
      for (int khf = 0; khf < 2; ++khf) {
        short8 af[4], bb[4];
#pragma unroll
        for (int m = 0; m < 4; ++m) {
          int row = wr + m * 16 + fr;
          int p = (khf * 4 + fq) ^ (row & 7);
          af[m] = *(const short8*)(smem + row * 128 + p * 16);
        }
#pragma unroll
        for (int n = 0; n < 4; ++n) {
          int row = wc + n * 16 + fr;
          int p = (khf * 4 + fq) ^ (row & 7);
          bb[n] = *(const short8*)(smem + 16384 + row * 128 + p * 16);
        }
#pragma unroll
        for (int m = 0; m < 4; ++m)
#pragma unroll
          for (int n = 0; n < 4; ++n)
            acc[m][n] = __builtin_amdgcn_mfma_f32_16x16x32_bf16(af[m], bb[n], acc[m][n], 0, 0, 0);
      }
      __syncthreads();
    }
  }

  float bs[4];
#pragma unroll
  for (int n = 0; n < 4; ++n) bs[n] = bias[ctile * 128 + wc + n * 16 + fr];

  if (MODE == 3) {
#pragma unroll
    for (int m = 0; m < 4; ++m) {
      int trow = ttile * 128 + wr + m * 16 + fq * 4;
#pragma unroll
      for (int n = 0; n < 4; ++n) {
        int oc = ctile * 128 + wc + n * 16 + fr;
        size_t o = (size_t)oc * 32768 + trow;
        float4 xv = *(const float4*)(xmct + o);
        float4 w;
        w.x = acc[m][n][0] + bs[n] + xv.x;
        w.y = acc[m][n][1] + bs[n] + xv.y;
        w.z = acc[m][n][2] + bs[n] + xv.z;
        w.w = acc[m][n][3] + bs[n] + xv.w;
        *(float4*)(outF + o) = w;
      }
    }
  } else {
    float sn[4] = {0, 0, 0, 0}, qn[4] = {0, 0, 0, 0};
#pragma unroll
    for (int m = 0; m < 4; ++m) {
#pragma unroll
      for (int j = 0; j < 4; ++j) {
        int t = ttile * 128 + wr + m * 16 + fq * 4 + j;
        float* yr = outF + (size_t)t * 256 + ctile * 128 + wc;
#pragma unroll
        for (int n = 0; n < 4; ++n) {
          float v = acc[m][n][j] + bs[n];
          yr[n * 16 + fr] = v;
          sn[n] += v;
          qn[n] += v * v;
        }
      }
    }
    // reduce over fq (lane bits 4,5): column partials over this wave's 64 rows
#pragma unroll
    for (int n = 0; n < 4; ++n) {
      float s = sn[n], q = qn[n];
      s += __shfl_xor(s, 16); s += __shfl_xor(s, 32);
      q += __shfl_xor(q, 16); q += __shfl_xor(q, 32);
      if (lane < 16) {
        int pi = (ttile * 2 + (wv >> 1)) * 256 + ctile * 128 + wc + n * 16 + fr;
        part[pi] = s;
        part[131072 + pi] = q;
      }
    }
  }
}

// ---------------- BN stats reduce: part [2][512][256] -> scale/shift ----------------
__global__ void stats2_k(const float* __restrict__ part, const float* __restrict__ g,
                         const float* __restrict__ be, float* __restrict__ sf) {
  __shared__ float sred[4][256], qred[4][256];
  int tid = threadIdx.x;
  int c = tid & 255, qd = tid >> 8;
  float s = 0, q = 0;
  for (int b = qd * 128; b < qd * 128 + 128; ++b) {
    s += part[b * 256 + c];
    q += part[131072 + b * 256 + c];
  }
  sred[qd][c] = s;
  qred[qd][c] = q;
  __syncthreads();
  if (qd == 0) {
    s = sred[0][c] + sred[1][c] + sred[2][c] + sred[3][c];
    q = qred[0][c] + qred[1][c] + qred[2][c] + qred[3][c];
    float mean = s * (1.0f / 32768.0f);
    float var = q * (1.0f / 32768.0f) - mean * mean;
    float a = g[c] * rsqrtf(var + 1e-5f);
    sf[c] = a;
    sf[256 + c] = be[c] - mean * a;
  }
}

// ---------------- BN apply (+leaky, +skip) ----------------
template <int V>
__global__ void bn_k(const float* __restrict__ y, const float* __restrict__ sf,
                     const float* __restrict__ skip, u16* __restrict__ pad,
                     float* __restrict__ f32o, u16* __restrict__ bfo) {
  int gid = blockIdx.x * 256 + threadIdx.x;
  int t = gid >> 5, c0 = (gid & 31) << 3;
  size_t base = (size_t)t * 256 + c0;
  float v[8];
  const float4* yp = (const float4*)(y + base);
  float4 y0 = yp[0], y1 = yp[1];
  const float4* ap = (const float4*)(sf + c0);
  float4 a0 = ap[0], a1 = ap[1];
  const float4* shp = (const float4*)(sf + 256 + c0);
  float4 s0 = shp[0], s1 = shp[1];
  v[0] = a0.x * y0.x + s0.x; v[1] = a0.y * y0.y + s0.y;
  v[2] = a0.z * y0.z + s0.z; v[3] = a0.w * y0.w + s0.w;
  v[4] = a1.x * y1.x + s1.x; v[5] = a1.y * y1.y + s1.y;
  v[6] = a1.z * y1.z + s1.z; v[7] = a1.w * y1.w + s1.w;
  if (V >= 1) {
    const float4* kp = (const float4*)(skip + base);
    float4 k0 = kp[0], k1 = kp[1];
    v[0] += k0.x; v[1] += k0.y; v[2] += k0.z; v[3] += k0.w;
    v[4] += k1.x; v[5] += k1.y; v[6] += k1.z; v[7] += k1.w;
  }
#pragma unroll
  for (int i = 0; i < 8; ++i) v[i] = v[i] > 0.0f ? v[i] : 0.01f * v[i];
  if (V <= 1) {
    int d = t >> 10, h = (t >> 5) & 31, w = t & 31;
    int prow = (d + 1) * 1156 + (h + 1) * 34 + (w + 1);
    uint4 pk;
    pk.x = (u32)f2bf(v[0]) | ((u32)f2bf(v[1]) << 16);
    pk.y = (u32)f2bf(v[2]) | ((u32)f2bf(v[3]) << 16);
    pk.z = (u32)f2bf(v[4]) | ((u32)f2bf(v[5]) << 16);
    pk.w = (u32)f2bf(v[6]) | ((u32)f2bf(v[7]) << 16);
    *(uint4*)(pad + (size_t)prow * 256 + c0) = pk;
  }
  if (V == 1) {
    float4 o0 = {v[0], v[1], v[2], v[3]}, o1 = {v[4], v[5], v[6], v[7]};
    float4* fp = (float4*)(f32o + base);
    fp[0] = o0; fp[1] = o1;
  }
  if (V == 2) {
    uint4 pk;
    pk.x = (u32)f2bf(v[0]) | ((u32)f2bf(v[1]) << 16);
    pk.y = (u32)f2bf(v[2]) | ((u32)f2bf(v[3]) << 16);
    pk.z = (u32)f2bf(v[4]) | ((u32)f2bf(v[5]) << 16);
    pk.w = (u32)f2bf(v[6]) | ((u32)f2bf(v[7]) << 16);
    *(uint4*)(bfo + base) = pk;
  }
}

// ---------------- xm = x + moe: writes xm_tc (in place), xm_ct, xm_pad ----------------
__global__ void xm_k(float* __restrict__ xt, const float* __restrict__ moe,
                     float* __restrict__ xmct, u16* __restrict__ pad) {
  __shared__ float ld[64][65];
  int tt = blockIdx.x, cc = blockIdx.y, tid = threadIdx.x;
#pragma unroll
  for (int k = 0; k < 16; ++k) {
    int idx = tid + k * 256;
    int tl = idx >> 6, cl = idx & 63;
    size_t o = (size_t)(tt * 64 + tl) * 256 + cc * 64 + cl;
    float v = xt[o] + moe[o];
    xt[o] = v;
    ld[tl][cl] = v;
    int t = tt * 64 + tl;
    int d = t >> 10, h = (t >> 5) & 31, w = t & 31;
    int prow = (d + 1) * 1156 + (h + 1) * 34 + (w + 1);
    pad[(size_t)prow * 256 + cc * 64 + cl] = f2bf(v);
  }
  __syncthreads();
#pragma unroll
  for (int k = 0; k < 16; ++k) {
    int idx = tid + k * 256;
    int cl = idx >> 6, tl = idx & 63;
    xmct[(size_t)(cc * 64 + cl) * 32768 + tt * 64 + tl] = ld[tl][cl];
  }
}

extern "C" void kernel_launch(void* const* d_in, const int* in_sizes, int n_in,
                              void* d_out, int out_size, void* d_ws, size_t ws_size,
                              hipStream_t stream) {
  (void)in_sizes; (void)n_in; (void)out_size; (void)ws_size;
  const float* x  = (const float*)d_in[0];
  const float* wg = (const float*)d_in[1];
  const float* w1 = (const float*)d_in[2];
  const float* b1 = (const float*)d_in[3];
  const float* w2 = (const float*)d_in[4];
  const float* b2 = (const float*)d_in[5];

  char* ws = (char*)d_ws;
  u16* tok    = (u16*)(ws + WS_TOK);
  float* xt   = (float*)(ws + WS_XT);
  float* xmct = (float*)(ws + WS_XMCT);
  float* gates= (float*)(ws + WS_GATES);
  float* part = (float*)(ws + WS_PART);
  float* moe  = (float*)(ws + WS_MOE);
  u16* P1     = (u16*)(ws + WS_P1);
  u16* P2     = (u16*)(ws + WS_P2);
  float* ybuf = (float*)(ws + WS_Y);
  u16* r2b    = (u16*)(ws + WS_R2);
  u16* wrb    = (u16*)(ws + WS_WRB);
  u16* w1p    = (u16*)(ws + WS_W1P);
  u16* w2p    = (u16*)(ws + WS_W2P);
  u16* c8p    = (u16*)(ws + WS_C8P);
  float* sf   = (float*)(ws + WS_SF);
  float* auxp = (float*)(ws + WS_AUXP);
  float* outp = (float*)d_out;

  halo_k<<<4913, 256, 0, stream>>>(P1, P2);
  trans_in_k<<<dim3(512, 4), 256, 0, stream>>>(x, xt, tok);
  pack_rb_k<<<1024, 256, 0, stream>>>((const float*)d_in[6], (const float*)d_in[10],
                                      (const float*)d_in[14], (const float*)d_in[18], wrb);
  pack_tr_k<<<dim3(16, 16), 256, 0, stream>>>(w1, w2, w1p, w2p);
  cvt_k<<<256, 256, 0, stream>>>((const float*)d_in[22], c8p, 65536);
  gate_k<<<128, 256, 0, stream>>>(xt, wg, gates, auxp);

  moe_k<<<256, 512, 0, stream>>>(tok, w1p, w2p, b1, b2, gates, moe);
  xm_k<<<dim3(512, 4), 256, 0, stream>>>(xt, moe, xmct, P1);

  // resblock 1
  gemm_k<0><<<dim3(256, 2), 256, 0, stream>>>(P1, wrb + 0 * 1769472, (const float*)d_in[7],
                                              ybuf, nullptr, part);
  stats2_k<<<1, 1024, 0, stream>>>(part, (const float*)d_in[8], (const float*)d_in[9], sf);
  bn_k<0><<<4096, 256, 0, stream>>>(ybuf, sf, nullptr, P2, nullptr, nullptr);
  gemm_k<0><<<dim3(256, 2), 256, 0, stream>>>(P2, wrb + 1 * 1769472, (const float*)d_in[11],
                                              ybuf, nullptr, part);
  stats2_k<<<1, 1024, 0, stream>>>(part, (const float*)d_in[12], (const float*)d_in[13], sf);
  bn_k<1><<<4096, 256, 0, stream>>>(ybuf, sf, xt, P1, xt, nullptr);

  // resblock 2
  gemm_k<0><<<dim3(256, 2), 256, 0, stream>>>(P1, wrb + 2 * 1769472, (const float*)d_in[15],
                                              ybuf, nullptr, part);
  stats2_k<<<1, 1024, 0, stream>>>(part, (const float*)d_in[16], (const float*)d_in[17], sf);
  bn_k<0><<<4096, 256, 0, stream>>>(ybuf, sf, nullptr, P2, nullptr, nullptr);
  gemm_k<0><<<dim3(256, 2), 256, 0, stream>>>(P2, wrb + 3 * 1769472, (const float*)d_in[19],
                                              ybuf, nullptr, part);
  stats2_k<<<1, 1024, 0, stream>>>(part, (const float*)d_in[20], (const float*)d_in[21], sf);
  bn_k<2><<<4096, 256, 0, stream>>>(ybuf, sf, xt, nullptr, nullptr, r2b);

  // final: out = xm + conv1x1(res)
  gemm_k<3><<<dim3(256, 2), 256, 0, stream>>>(r2b, c8p, (const float*)d_in[23], outp,
                                              xmct, nullptr);
  aux_k<<<1, 64, 0, stream>>>(auxp, outp + 8388608);
}

// Round 5
// 718.341 us; speedup vs baseline: 1.6099x; 1.0833x over previous
//
#include <hip/hip_runtime.h>
#include <stdint.h>

typedef __attribute__((ext_vector_type(8))) short short8;
typedef __attribute__((ext_vector_type(4))) float f32x4;
typedef unsigned short u16;
typedef unsigned int u32;
typedef unsigned long long u64;

// ---------------- workspace layout (bytes) ----------------
#define WS_TOK   0ull           // tokens bf16 [32768][256]            16 MB
#define WS_XT    16777216ull    // x_t -> xm_tc -> r1 fp32 [T][C]      32 MB
#define WS_XMCT  50331648ull    // xm fp32 [C][T]                      32 MB
#define WS_GATES 83886080ull    // gw fp32 [T][2] (512KB) | tpos u32 [T][2] (512KB)
#define WS_H     84934656ull    // perm/meta/sel region (16 MB)
#define WS_MOE   101711872ull   // (unused)
#define WS_P1    135266304ull   // padded bf16 [34^3][256]             19.2MB
#define WS_P2    155389952ull
#define WS_Y     175513600ull   // conv y fp32 [T][256] / earlier: eo bf16 [66560][256]
#define WS_R2    209068032ull   // r2 bf16 [T][256] (eo tail overlaps, timeline-safe)
#define WS_WRB   225845248ull   // packed rb conv w bf16 [4][27][256][256]
#define WS_W1P   240001024ull
#define WS_W2P   241049600ull
#define WS_C8P   242098176ull
#define WS_PART  242229248ull   // bn partials [2][512][256] fp32 (1MB)
#define WS_SF    243277824ull   // bn scale/shift [2][256]
#define WS_AUXP  243279872ull   // aux partials [128][16]

#define WS_PERM  (WS_H + 0x00000ull)   // u32 [66560]
#define WS_TBL   (WS_H + 0x60000ull)   // u32 [520]
#define WS_META  (WS_H + 0x70000ull)   // u32 [1]
#define WS_BCNT  (WS_H + 0x80000ull)   // u32 [128][8]
#define WS_BOFF  (WS_H + 0x90000ull)   // u32 [128][8]
#define WS_SEL   (WS_H + 0x100000ull)  // u32 [32768]

__device__ __forceinline__ u16 f2bf(float f) {
  u32 x = __float_as_uint(f);
  u32 r = x + 0x7fffu + ((x >> 16) & 1u);
  return (u16)(r >> 16);
}

// ---------------- transpose x [C][T] -> x_t fp32 + tokens bf16 [T][C] ----------------
__global__ void trans_in_k(const float* __restrict__ x, float* __restrict__ xt,
                           u16* __restrict__ tok) {
  __shared__ float ld[64][65];
  int tt = blockIdx.x, cc = blockIdx.y, tid = threadIdx.x;
#pragma unroll
  for (int k = 0; k < 16; ++k) {
    int idx = tid + k * 256;
    int cl = idx >> 6, j = idx & 63;
    ld[cl][j] = x[(size_t)(cc * 64 + cl) * 32768 + tt * 64 + j];
  }
  __syncthreads();
#pragma unroll
  for (int k = 0; k < 16; ++k) {
    int idx = tid + k * 256;
    int tl = idx >> 6, cl = idx & 63;
    float v = ld[cl][tl];
    size_t o = (size_t)(tt * 64 + tl) * 256 + cc * 64 + cl;
    xt[o] = v;
    tok[o] = f2bf(v);
  }
}

// ---------------- pack resblock conv weights ----------------
__global__ void pack_rb_k(const float* __restrict__ w0, const float* __restrict__ w1,
                          const float* __restrict__ w2, const float* __restrict__ w3,
                          u16* __restrict__ out) {
  __shared__ float ld[6912];
  int conv = blockIdx.x >> 8, blk = blockIdx.x & 255, tid = threadIdx.x;
  const float* src = conv == 0 ? w0 : conv == 1 ? w1 : conv == 2 ? w2 : w3;
  size_t base = (size_t)blk * 256 * 27;
#pragma unroll
  for (int k = 0; k < 27; ++k) ld[tid + k * 256] = src[base + tid + k * 256];
  __syncthreads();
  u16* dst = out + (size_t)conv * 27 * 65536;
  int n = blk * 256 + tid;
#pragma unroll
  for (int tap = 0; tap < 27; ++tap)
    dst[(size_t)tap * 65536 + n] = f2bf(ld[tid * 27 + tap]);
}

// ---------------- transpose-pack w1/w2 256x256 matrices to [N][K] bf16 ----------------
__global__ void pack_tr_k(const float* __restrict__ w1, const float* __restrict__ w2,
                          u16* __restrict__ w1p, u16* __restrict__ w2p) {
  __shared__ float ld[64][65];
  int m = blockIdx.y, tile = blockIdx.x, tid = threadIdx.x;
  const float* src = (m < 8) ? (w1 + (size_t)m * 65536) : (w2 + (size_t)(m - 8) * 65536);
  u16* dst = (m < 8) ? (w1p + (size_t)m * 65536) : (w2p + (size_t)(m - 8) * 65536);
  int r0 = (tile >> 2) * 64, c0 = (tile & 3) * 64;
#pragma unroll
  for (int k = 0; k < 16; ++k) {
    int idx = tid + k * 256;
    int rr = idx >> 6, cc = idx & 63;
    ld[rr][cc] = src[(size_t)(r0 + rr) * 256 + c0 + cc];
  }
  __syncthreads();
#pragma unroll
  for (int k = 0; k < 16; ++k) {
    int idx = tid + k * 256;
    int cc = idx >> 6, rr = idx & 63;
    dst[(size_t)(c0 + cc) * 256 + r0 + rr] = f2bf(ld[rr][cc]);
  }
}

__global__ void cvt_k(const float* __restrict__ in, u16* __restrict__ out, int n) {
  int i = blockIdx.x * 256 + threadIdx.x;
  if (i < n) out[i] = f2bf(in[i]);
}

// ---------------- zero halo rows of both padded buffers ----------------
__global__ void halo_k(u16* __restrict__ P1, u16* __restrict__ P2) {
  int gid = blockIdx.x * 256 + threadIdx.x;
  int r = gid >> 5, o = (gid & 31) << 3;
  if (r >= 39304) return;
  int d = r / 1156, rem = r - d * 1156, h = rem / 34, w = rem - h * 34;
  if (d >= 1 && d <= 32 && h >= 1 && h <= 32 && w >= 1 && w <= 32) return;
  uint4 z = {0u, 0u, 0u, 0u};
  *(uint4*)(P1 + (size_t)r * 256 + o) = z;
  *(uint4*)(P2 + (size_t)r * 256 + o) = z;
}

// ---------------- gating: softmax + top2 + aux + sparse bookkeeping ----------------
__global__ void gate_k(const float* __restrict__ xt, const float* __restrict__ wg,
                       float* __restrict__ gw, u32* __restrict__ sel,
                       u32* __restrict__ blk_cnt, float* __restrict__ auxp) {
  __shared__ float wgs[2048];
  __shared__ float ax[4][16];
  __shared__ u32 bc[4][8];
  int tid = threadIdx.x;
#pragma unroll
  for (int k = 0; k < 8; ++k) wgs[tid + k * 256] = wg[tid + k * 256];
  __syncthreads();
  int t = blockIdx.x * 256 + tid;
  int lane = tid & 63, wv = tid >> 6;
  float l[8] = {0, 0, 0, 0, 0, 0, 0, 0};
  const float* xr = xt + (size_t)t * 256;
  for (int c = 0; c < 256; c += 4) {
    float4 xv = *(const float4*)(xr + c);
#pragma unroll
    for (int e = 0; e < 8; ++e)
      l[e] += xv.x * wgs[c * 8 + e] + xv.y * wgs[(c + 1) * 8 + e] +
              xv.z * wgs[(c + 2) * 8 + e] + xv.w * wgs[(c + 3) * 8 + e];
  }
  float mx = l[0];
#pragma unroll
  for (int e = 1; e < 8; ++e) mx = fmaxf(mx, l[e]);
  float p[8], sum = 0.f;
#pragma unroll
  for (int e = 0; e < 8; ++e) { p[e] = __expf(l[e] - mx); sum += p[e]; }
  float inv = 1.0f / sum;
#pragma unroll
  for (int e = 0; e < 8; ++e) p[e] *= inv;
  int i0 = 0; float v0 = p[0];
#pragma unroll
  for (int e = 1; e < 8; ++e) if (p[e] > v0) { v0 = p[e]; i0 = e; }
  int i1 = -1; float v1 = -1.0f;
#pragma unroll
  for (int e = 0; e < 8; ++e) if (e != i0 && p[e] > v1) { v1 = p[e]; i1 = e; }
  float wsum = v0 + v1;
  gw[t * 2] = v0 / wsum;
  gw[t * 2 + 1] = v1 / wsum;
  sel[t] = (u32)i0 | ((u32)i1 << 4);
  // per-block expert membership counts
  u64 mm[8];
#pragma unroll
  for (int e = 0; e < 8; ++e) mm[e] = __ballot(i0 == e || i1 == e);
  if (lane == 0) {
#pragma unroll
    for (int e = 0; e < 8; ++e) bc[wv][e] = (u32)__popcll(mm[e]);
  }
  // aux partials
#pragma unroll
  for (int e = 0; e < 8; ++e) {
    float ps = p[e];
    float cn = (e == i0 || e == i1) ? 1.0f : 0.0f;
    for (int o = 32; o; o >>= 1) { ps += __shfl_down(ps, o); cn += __shfl_down(cn, o); }
    if (lane == 0) { ax[wv][e] = ps; ax[wv][8 + e] = cn; }
  }
  __syncthreads();
  if (tid < 16)
    auxp[blockIdx.x * 16 + tid] = ax[0][tid] + ax[1][tid] + ax[2][tid] + ax[3][tid];
  if (tid < 8)
    blk_cnt[blockIdx.x * 8 + tid] = bc[0][tid] + bc[1][tid] + bc[2][tid] + bc[3][tid];
}

__global__ void aux_k(const float* __restrict__ auxp, float* __restrict__ out) {
  __shared__ float s[16];
  int i = threadIdx.x;
  if (i < 16) {
    float a = 0;
    for (int b = 0; b < 128; ++b) a += auxp[b * 16 + i];
    s[i] = a;
  }
  __syncthreads();
  if (i == 0) {
    float r = 0;
    for (int e = 0; e < 8; ++e)
      r += (s[8 + e] * (1.0f / 32768.0f)) * (s[e] * (1.0f / 32768.0f));
    out[0] = r * 8.0f;
  }
}

// ---------------- scan: block counts -> absolute offsets, chunk table, perm pads ----
__global__ void scan_k(const u32* __restrict__ blk_cnt, u32* __restrict__ blkoff,
                       u32* __restrict__ tbl, u32* __restrict__ meta,
                       u32* __restrict__ perm) {
  __shared__ u32 tot[8], base[8], nck[8], cbase[8];
  int tid = threadIdx.x;
  if (tid < 8) {
    u32 run = 0;
    for (int b = 0; b < 128; ++b) {
      blkoff[b * 8 + tid] = run;
      run += blk_cnt[b * 8 + tid];
    }
    tot[tid] = run;
  }
  __syncthreads();
  if (tid == 0) {
    u32 acc = 0, c = 0;
    for (int e = 0; e < 8; ++e) {
      base[e] = acc;
      u32 nc = (tot[e] + 127) >> 7;
      nck[e] = nc;
      cbase[e] = c;
      acc += nc << 7;
      c += nc;
    }
    meta[0] = c;
  }
  __syncthreads();
  for (int i = tid; i < 1024; i += 256) blkoff[i] += base[i & 7];
  if (tid < 8) {
    for (u32 k = 0; k < nck[tid]; ++k)
      tbl[cbase[tid] + k] = ((base[tid] + (k << 7)) << 4) | (u32)tid;
    for (u32 sl = base[tid] + tot[tid]; sl < base[tid] + (nck[tid] << 7); ++sl)
      perm[sl] = 0;
  }
}

// ---------------- scatter: deterministic positions via ballot ranks ----------------
__global__ void scatter_k(const u32* __restrict__ sel, const u32* __restrict__ blkoff,
                          u32* __restrict__ perm, u32* __restrict__ tpos) {
  __shared__ u32 wcnt[4][8];
  int tid = threadIdx.x, b = blockIdx.x;
  int lane = tid & 63, wv = tid >> 6;
  int t = b * 256 + tid;
  u32 s = sel[t];
  int i0 = s & 15, i1 = (s >> 4) & 15;
  u64 mm[8];
#pragma unroll
  for (int e = 0; e < 8; ++e) mm[e] = __ballot(i0 == e || i1 == e);
  if (lane == 0) {
#pragma unroll
    for (int e = 0; e < 8; ++e) wcnt[wv][e] = (u32)__popcll(mm[e]);
  }
  __syncthreads();
  u64 lt = (1ull << lane) - 1ull;
#pragma unroll
  for (int e = 0; e < 8; ++e) {
    bool is0 = (i0 == e), is1 = (i1 == e);
    if (is0 || is1) {
      u32 woff = 0;
#pragma unroll
      for (int w = 0; w < 4; ++w)
        if (w < wv) woff += wcnt[w][e];
      u32 pos = blkoff[b * 8 + e] + woff + (u32)__popcll(mm[e] & lt);
      perm[pos] = (u32)t;
      tpos[t * 2 + (is0 ? 0 : 1)] = pos;
    }
  }
}

// ---------------- sparse MoE GEMM: one expert-chunk of 128 gathered tokens ----------
// LDS: tokG 64KB | Bs 32KB | Hs 64KB. GEMM1 swapped -> Hs b64 writes; GEMM2 -> eo bf16.
__global__ __launch_bounds__(512, 2) void moe_gemm_k(
    const u16* __restrict__ tok, const u32* __restrict__ perm,
    const u32* __restrict__ tbl, const u32* __restrict__ meta,
    const u16* __restrict__ w1p, const u16* __restrict__ w2p,
    const float* __restrict__ b1, const float* __restrict__ b2,
    u16* __restrict__ eo) {
  __shared__ __attribute__((aligned(16))) unsigned char smem[163840];
  const int bid = blockIdx.x;
  if ((u32)bid >= meta[0]) return;
  const u32 ent = tbl[bid];
  const int e = (int)(ent & 15u);
  const int slot0 = (int)(ent >> 4);
  const int tid = threadIdx.x;
  const int lane = tid & 63;
  const int wv = tid >> 6;
  const int wr = (wv >> 2) * 64;  // t-slice
  const int wc = (wv & 3) * 64;   // c-slice
  const int fq = lane >> 4, fr = lane & 15;
  const u16* w1e = w1p + e * 65536;
  const u16* w2e = w2p + e * 65536;

  // stage gathered tok rows [128][256] (per-lane global source, linear LDS dest)
#pragma unroll
  for (int it = 0; it < 8; ++it) {
    int s = tid + it * 512;
    int r = s >> 5, seg = s & 31;
    int cole = ((seg >> 3) << 6) + (((seg & 7) ^ (r & 7)) << 3);
    u32 rowtok = perm[slot0 + r];
    __builtin_amdgcn_global_load_lds(
        (const __attribute__((address_space(1))) u32*)(tok + (size_t)rowtok * 256 + cole),
        (__attribute__((address_space(3))) u32*)(smem + s * 16), 16, 0, 0);
  }

  // ---- GEMM1 (swapped): acc1[mc][nt] = w1-rows x tok-rows -> h^T frags ----
  f32x4 acc1[4][4];
#pragma unroll
  for (int mc = 0; mc < 4; ++mc)
#pragma unroll
    for (int nt = 0; nt < 4; ++nt) acc1[mc][nt] = (f32x4){0.f, 0.f, 0.f, 0.f};

#pragma unroll 1
  for (int kc = 0; kc < 4; ++kc) {
#pragma unroll
    for (int it = 0; it < 4; ++it) {
      int s = tid + it * 512;
      int r = s >> 3;
      int sub = (s & 7) ^ (r & 7);
      __builtin_amdgcn_global_load_lds(
          (const __attribute__((address_space(1))) u32*)(w1e + (size_t)r * 256 + kc * 64 + sub * 8),
          (__attribute__((address_space(3))) u32*)(smem + 65536 + s * 16), 16, 0, 0);
    }
    __syncthreads();
#pragma unroll
    for (int khf = 0; khf < 2; ++khf) {
      short8 af1[4], bt[4];
#pragma unroll
      for (int mc = 0; mc < 4; ++mc) {
        int row = wc + mc * 16 + fr;
        int p = (khf * 4 + fq) ^ (row & 7);
        af1[mc] = *(const short8*)(smem + 65536 + row * 128 + p * 16);
      }
#pragma unroll
      for (int nt = 0; nt < 4; ++nt) {
        int row = wr + nt * 16 + fr;
        int p = (khf * 4 + fq) ^ (row & 7);
        bt[nt] = *(const short8*)(smem + row * 512 + kc * 128 + p * 16);
      }
#pragma unroll
      for (int mc = 0; mc < 4; ++mc)
#pragma unroll
        for (int nt = 0; nt < 4; ++nt)
          acc1[mc][nt] = __builtin_amdgcn_mfma_f32_16x16x32_bf16(af1[mc], bt[nt], acc1[mc][nt], 0, 0, 0);
    }
    __syncthreads();
  }

  // epilogue: h = gelu(acc1 + b1[c]) -> Hs b64 swizzled writes
#pragma unroll
  for (int mc = 0; mc < 4; ++mc) {
    int k0 = wc + mc * 16 + fq * 4;
    float4 bv = *(const float4*)(b1 + e * 256 + k0);
#pragma unroll
    for (int nt = 0; nt < 4; ++nt) {
      int t = wr + nt * 16 + fr;
      u64 pk = 0;
#pragma unroll
      for (int j = 0; j < 4; ++j) {
        float v = acc1[mc][nt][j] + ((const float*)&bv)[j];
        float u = 1.5957691216057308f * (v + 0.044715f * v * v * v);
        float g = v / (1.0f + __expf(-u));
        pk |= (u64)f2bf(g) << (16 * j);
      }
      *(u64*)(smem + 98304 + t * 512 + ((k0 * 2) ^ ((t & 7) << 4))) = pk;
    }
  }

  // ---- GEMM2: acc2[m][n] = h-rows x w2-rows ----
  f32x4 acc2[4][4];
#pragma unroll
  for (int m = 0; m < 4; ++m)
#pragma unroll
    for (int n = 0; n < 4; ++n) acc2[m][n] = (f32x4){0.f, 0.f, 0.f, 0.f};

#pragma unroll 1
  for (int kc = 0; kc < 4; ++kc) {
#pragma unroll
    for (int it = 0; it < 4; ++it) {
      int s = tid + it * 512;
      int r = s >> 3;
      int sub = (s & 7) ^ (r & 7);
      __builtin_amdgcn_global_load_lds(
          (const __attribute__((address_space(1))) u32*)(w2e + (size_t)r * 256 + kc * 64 + sub * 8),
          (__attribute__((address_space(3))) u32*)(smem + 65536 + s * 16), 16, 0, 0);
    }
    __syncthreads();
#pragma unroll
    for (int khf = 0; khf < 2; ++khf) {
      short8 af[4], bb[4];
#pragma unroll
      for (int m = 0; m < 4; ++m) {
        int row = wr + m * 16 + fr;
        int col = (kc * 128 + (khf * 4 + fq) * 16) ^ ((row & 7) << 4);
        af[m] = *(const short8*)(smem + 98304 + row * 512 + col);
      }
#pragma unroll
      for (int n = 0; n < 4; ++n) {
        int row = wc + n * 16 + fr;
        int p = (khf * 4 + fq) ^ (row & 7);
        bb[n] = *(const short8*)(smem + 65536 + row * 128 + p * 16);
      }
#pragma unroll
      for (int m = 0; m < 4; ++m)
#pragma unroll
        for (int n = 0; n < 4; ++n)
          acc2[m][n] = __builtin_amdgcn_mfma_f32_16x16x32_bf16(af[m], bb[n], acc2[m][n], 0, 0, 0);
    }
    __syncthreads();
  }

  float bs2[4];
#pragma unroll
  for (int n = 0; n < 4; ++n) bs2[n] = b2[e * 256 + wc + n * 16 + fr];
#pragma unroll
  for (int m = 0; m < 4; ++m)
#pragma unroll
    for (int j = 0; j < 4; ++j) {
      int rowslot = slot0 + wr + m * 16 + fq * 4 + j;
      u16* er = eo + (size_t)rowslot * 256 + wc;
#pragma unroll
      for (int n = 0; n < 4; ++n) er[n * 16 + fr] = f2bf(acc2[m][n][j] + bs2[n]);
    }
}

// ---------------- combine: xm = x + g0*eo[p0] + g1*eo[p1]; write xt/xmct/pad --------
__global__ void combine_k(float* __restrict__ xt, const u16* __restrict__ eo,
                          const float* __restrict__ gw, const u32* __restrict__ tpos,
                          float* __restrict__ xmct, u16* __restrict__ pad) {
  __shared__ float ld[64][65];
  __shared__ u32 pp[64][2];
  __shared__ float gg[64][2];
  int tt = blockIdx.x, cc = blockIdx.y, tid = threadIdx.x;
  if (tid < 128) {
    int tl = tid >> 1, s = tid & 1;
    int t = tt * 64 + tl;
    pp[tl][s] = tpos[t * 2 + s];
    gg[tl][s] = gw[t * 2 + s];
  }
  __syncthreads();
#pragma unroll
  for (int k = 0; k < 16; ++k) {
    int idx = tid + k * 256;
    int tl = idx >> 6, cl = idx & 63;
    int c = cc * 64 + cl;
    size_t o = (size_t)(tt * 64 + tl) * 256 + c;
    float e0 = __uint_as_float((u32)eo[(size_t)pp[tl][0] * 256 + c] << 16);
    float e1 = __uint_as_float((u32)eo[(size_t)pp[tl][1] * 256 + c] << 16);
    float v = xt[o] + gg[tl][0] * e0 + gg[tl][1] * e1;
    xt[o] = v;
    ld[tl][cl] = v;
    int t = tt * 64 + tl;
    int d = t >> 10, h = (t >> 5) & 31, w = t & 31;
    int prow = (d + 1) * 1156 + (h + 1) * 34 + (w + 1);
    pad[(size_t)prow * 256 + c] = f2bf(v);
  }
  __syncthreads();
#pragma unroll
  for (int k = 0; k < 16; ++k) {
    int idx = tid + k * 256;
    int cl = idx >> 6, tl = idx & 63;
    xmct[(size_t)(cc * 64 + cl) * 32768 + tt * 64 + tl] = ld[tl][cl];
  }
}

// ---------------- unified MFMA GEMM (convs + final 1x1) ----------------
// MODE 0: conv3x3x3 from padded buffer (XCD-swizzled ttile), y fp32 + BN partials
// MODE 3: final 1x1 conv, out[oc][t] = acc + bias + xmct[oc][t]
template <int MODE>
__global__ __launch_bounds__(256, 2) void gemm_k(
    const u16* __restrict__ A, const u16* __restrict__ Bw,
    const float* __restrict__ bias, float* __restrict__ outF,
    const float* __restrict__ xmct, float* __restrict__ part) {
  __shared__ __attribute__((aligned(16))) unsigned char smem[32768];
  const int tid = threadIdx.x;
  const int bx = blockIdx.x;
  const int ttile = (MODE == 0) ? ((bx & 7) * 32 + (bx >> 3)) : bx;  // XCD-bijective
  const int ctile = blockIdx.y;
  const int lane = tid & 63;
  const int wv = tid >> 6;
  const int wr = (wv >> 1) << 6;
  const int wc = (wv & 1) << 6;
  const int fq = lane >> 4;
  const int fr = lane & 15;

  int aoff[4], boff[4];
#pragma unroll
  for (int it = 0; it < 4; ++it) {
    int s = tid + it * 256;
    int r = s >> 3;
    int lsg = (s & 7) ^ (r & 7);
    if (MODE == 0) {
      int dd = ttile >> 3;
      int h0 = (ttile & 7) << 2;
      int base = dd * 1156 + (h0 + (r >> 5)) * 34 + (r & 31);
      aoff[it] = base * 256 + lsg * 8;
    } else {
      aoff[it] = (ttile * 128 + r) * 256 + lsg * 8;
    }
    boff[it] = (ctile * 128 + r) * 256 + lsg * 8;
  }

  f32x4 acc[4][4];
#pragma unroll
  for (int m = 0; m < 4; ++m)
#pragma unroll
    for (int n = 0; n < 4; ++n) acc[m][n] = (f32x4){0.f, 0.f, 0.f, 0.f};

  const int nTap = (MODE == 0) ? 27 : 1;
#pragma unroll 1
  for (int tap = 0; tap < nTap; ++tap) {
    int atap = 0, btap = 0;
    if (MODE == 0) {
      atap = ((tap / 9) * 1156 + ((tap / 3) % 3) * 34 + (tap % 3)) * 256;
      btap = tap * 65536;
    }
#pragma unroll 1
    for (int kc = 0; kc < 4; ++kc) {
      const u16* Ak = A + atap + kc * 64;
      const u16* Bk = Bw + btap + kc * 64;
#pragma unroll
      for (int it = 0; it < 4; ++it) {
        __builtin_amdgcn_global_load_lds(
            (const __attribute__((address_space(1))) u32*)(Ak + aoff[it]),
            (__attribute__((address_space(3))) u32*)(smem + (tid + it * 256) * 16),
            16, 0, 0);
        __builtin_amdgcn_global_load_lds(
            (const __attribute__((address_space(1))) u32*)(Bk + boff[it]),
            (__attribute__((address_space(3))) u32*)(smem + 16384 + (tid + it * 256) * 16),
            16, 0, 0);
      }
      __syncthreads();
#pragma unroll
      for (int khf = 0; khf < 2; ++khf) {
        short8 af[4], bb[4];
#pragma unroll
        for (int m = 0; m < 4; ++m) {
          int row = wr + m * 16 + fr;
          int p = (khf * 4 + fq) ^ (row & 7);
          af[m] = *(const short8*)(smem + row * 128 + p * 16);
        }
#pragma unroll
        for (int n = 0; n < 4; ++n) {
          int row = wc + n * 16 + fr;
          int p = (khf * 4 + fq) ^ (row & 7);
          bb[n] = *(const short8*)(smem + 16384 + row * 128 + p * 16);
        }
#pragma unroll
        for (int m = 0; m < 4; ++m)
#pragma unroll
          for (int n = 0; n < 4; ++n)
            acc[m][n] = __builtin_amdgcn_mfma_f32_16x16x32_bf16(af[m], bb[n], acc[m][n], 0, 0, 0);
      }
      __syncthreads();
    }
  }

  float bs[4];
#pragma unroll
  for (int n = 0; n < 4; ++n) bs[n] = bias[ctile * 128 + wc + n * 16 + fr];

  if (MODE == 3) {
#pragma unroll
    for (int m = 0; m < 4; ++m) {
      int trow = ttile * 128 + wr + m * 16 + fq * 4;
#pragma unroll
      for (int n = 0; n < 4; ++n) {
        int oc = ctile * 128 + wc + n * 16 + fr;
        size_t o = (size_t)oc * 32768 + trow;
        float4 xv = *(const float4*)(xmct + o);
        float4 w;
        w.x = acc[m][n][0] + bs[n] + xv.x;
        w.y = acc[m][n][1] + bs[n] + xv.y;
        w.z = acc[m][n][2] + bs[n] + xv.z;
        w.w = acc[m][n][3] + bs[n] + xv.w;
        *(float4*)(outF + o) = w;
      }
    }
  } else {
    float sn[4] = {0, 0, 0, 0}, qn[4] = {0, 0, 0, 0};
#pragma unroll
    for (int m = 0; m < 4; ++m) {
#pragma unroll
      for (int j = 0; j < 4; ++j) {
        int t = ttile * 128 + wr + m * 16 + fq * 4 + j;
        float* yr = outF + (size_t)t * 256 + ctile * 128 + wc;
#pragma unroll
        for (int n = 0; n < 4; ++n) {
          float v = acc[m][n][j] + bs[n];
          yr[n * 16 + fr] = v;
          sn[n] += v;
          qn[n] += v * v;
        }
      }
    }
#pragma unroll
    for (int n = 0; n < 4; ++n) {
      float s = sn[n], q = qn[n];
      s += __shfl_xor(s, 16); s += __shfl_xor(s, 32);
      q += __shfl_xor(q, 16); q += __shfl_xor(q, 32);
      if (lane < 16) {
        int pi = (ttile * 2 + (wv >> 1)) * 256 + ctile * 128 + wc + n * 16 + fr;
        part[pi] = s;
        part[131072 + pi] = q;
      }
    }
  }
}

// ---------------- BN stats reduce ----------------
__global__ void stats2_k(const float* __restrict__ part, const float* __restrict__ g,
                         const float* __restrict__ be, float* __restrict__ sf) {
  __shared__ float sred[4][256], qred[4][256];
  int tid = threadIdx.x;
  int c = tid & 255, qd = tid >> 8;
  float s = 0, q = 0;
  for (int b = qd * 128; b < qd * 128 + 128; ++b) {
    s += part[b * 256 + c];
    q += part[131072 + b * 256 + c];
  }
  sred[qd][c] = s;
  qred[qd][c] = q;
  __syncthreads();
  if (qd == 0) {
    s = sred[0][c] + sred[1][c] + sred[2][c] + sred[3][c];
    q = qred[0][c] + qred[1][c] + qred[2][c] + qred[3][c];
    float mean = s * (1.0f / 32768.0f);
    float var = q * (1.0f / 32768.0f) - mean * mean;
    float a = g[c] * rsqrtf(var + 1e-5f);
    sf[c] = a;
    sf[256 + c] = be[c] - mean * a;
  }
}

// ---------------- BN apply (+leaky, +skip) ----------------
template <int V>
__global__ void bn_k(const float* __restrict__ y, const float* __restrict__ sf,
                     const float* __restrict__ skip, u16* __restrict__ pad,
                     float* __restrict__ f32o, u16* __restrict__ bfo) {
  int gid = blockIdx.x * 256 + threadIdx.x;
  int t = gid >> 5, c0 = (gid & 31) << 3;
  size_t base = (size_t)t * 256 + c0;
  float v[8];
  const float4* yp = (const float4*)(y + base);
  float4 y0 = yp[0], y1 = yp[1];
  const float4* ap = (const float4*)(sf + c0);
  float4 a0 = ap[0], a1 = ap[1];
  const float4* shp = (const float4*)(sf + 256 + c0);
  float4 s0 = shp[0], s1 = shp[1];
  v[0] = a0.x * y0.x + s0.x; v[1] = a0.y * y0.y + s0.y;
  v[2] = a0.z * y0.z + s0.z; v[3] = a0.w * y0.w + s0.w;
  v[4] = a1.x * y1.x + s1.x; v[5] = a1.y * y1.y + s1.y;
  v[6] = a1.z * y1.z + s1.z; v[7] = a1.w * y1.w + s1.w;
  if (V >= 1) {
    const float4* kp = (const float4*)(skip + base);
    float4 k0 = kp[0], k1 = kp[1];
    v[0] += k0.x; v[1] += k0.y; v[2] += k0.z; v[3] += k0.w;
    v[4] += k1.x; v[5] += k1.y; v[6] += k1.z; v[7] += k1.w;
  }
#pragma unroll
  for (int i = 0; i < 8; ++i) v[i] = v[i] > 0.0f ? v[i] : 0.01f * v[i];
  if (V <= 1) {
    int d = t >> 10, h = (t >> 5) & 31, w = t & 31;
    int prow = (d + 1) * 1156 + (h + 1) * 34 + (w + 1);
    uint4 pk;
    pk.x = (u32)f2bf(v[0]) | ((u32)f2bf(v[1]) << 16);
    pk.y = (u32)f2bf(v[2]) | ((u32)f2bf(v[3]) << 16);
    pk.z = (u32)f2bf(v[4]) | ((u32)f2bf(v[5]) << 16);
    pk.w = (u32)f2bf(v[6]) | ((u32)f2bf(v[7]) << 16);
    *(uint4*)(pad + (size_t)prow * 256 + c0) = pk;
  }
  if (V == 1) {
    float4 o0 = {v[0], v[1], v[2], v[3]}, o1 = {v[4], v[5], v[6], v[7]};
    float4* fp = (float4*)(f32o + base);
    fp[0] = o0; fp[1] = o1;
  }
  if (V == 2) {
    uint4 pk;
    pk.x = (u32)f2bf(v[0]) | ((u32)f2bf(v[1]) << 16);
    pk.y = (u32)f2bf(v[2]) | ((u32)f2bf(v[3]) << 16);
    pk.z = (u32)f2bf(v[4]) | ((u32)f2bf(v[5]) << 16);
    pk.w = (u32)f2bf(v[6]) | ((u32)f2bf(v[7]) << 16);
    *(uint4*)(bfo + base) = pk;
  }
}

extern "C" void kernel_launch(void* const* d_in, const int* in_sizes, int n_in,
                              void* d_out, int out_size, void* d_ws, size_t ws_size,
                              hipStream_t stream) {
  (void)in_sizes; (void)n_in; (void)out_size; (void)ws_size;
  const float* x  = (const float*)d_in[0];
  const float* wg = (const float*)d_in[1];
  const float* w1 = (const float*)d_in[2];
  const float* b1 = (const float*)d_in[3];
  const float* w2 = (const float*)d_in[4];
  const float* b2 = (const float*)d_in[5];

  char* ws = (char*)d_ws;
  u16* tok    = (u16*)(ws + WS_TOK);
  float* xt   = (float*)(ws + WS_XT);
  float* xmct = (float*)(ws + WS_XMCT);
  float* gw   = (float*)(ws + WS_GATES);
  u32* tpos   = (u32*)(ws + WS_GATES + 0x80000ull);
  u32* perm   = (u32*)(ws + WS_PERM);
  u32* tbl    = (u32*)(ws + WS_TBL);
  u32* meta   = (u32*)(ws + WS_META);
  u32* bcnt   = (u32*)(ws + WS_BCNT);
  u32* boff   = (u32*)(ws + WS_BOFF);
  u32* selb   = (u32*)(ws + WS_SEL);
  u16* P1     = (u16*)(ws + WS_P1);
  u16* P2     = (u16*)(ws + WS_P2);
  float* ybuf = (float*)(ws + WS_Y);
  u16* eo     = (u16*)(ws + WS_Y);   // eo lives in Y before convs start
  u16* r2b    = (u16*)(ws + WS_R2);
  u16* wrb    = (u16*)(ws + WS_WRB);
  u16* w1p    = (u16*)(ws + WS_W1P);
  u16* w2p    = (u16*)(ws + WS_W2P);
  u16* c8p    = (u16*)(ws + WS_C8P);
  float* part = (float*)(ws + WS_PART);
  float* sf   = (float*)(ws + WS_SF);
  float* auxp = (float*)(ws + WS_AUXP);
  float* outp = (float*)d_out;

  halo_k<<<4913, 256, 0, stream>>>(P1, P2);
  trans_in_k<<<dim3(512, 4), 256, 0, stream>>>(x, xt, tok);
  pack_rb_k<<<1024, 256, 0, stream>>>((const float*)d_in[6], (const float*)d_in[10],
                                      (const float*)d_in[14], (const float*)d_in[18], wrb);
  pack_tr_k<<<dim3(16, 16), 256, 0, stream>>>(w1, w2, w1p, w2p);
  cvt_k<<<256, 256, 0, stream>>>((const float*)d_in[22], c8p, 65536);

  gate_k<<<128, 256, 0, stream>>>(xt, wg, gw, selb, bcnt, auxp);
  scan_k<<<1, 256, 0, stream>>>(bcnt, boff, tbl, meta, perm);
  scatter_k<<<128, 256, 0, stream>>>(selb, boff, perm, tpos);
  moe_gemm_k<<<520, 512, 0, stream>>>(tok, perm, tbl, meta, w1p, w2p, b1, b2, eo);
  combine_k<<<dim3(512, 4), 256, 0, stream>>>(xt, eo, gw, tpos, xmct, P1);

  // resblock 1
  gemm_k<0><<<dim3(256, 2), 256, 0, stream>>>(P1, wrb + 0 * 1769472, (const float*)d_in[7],
                                              ybuf, nullptr, part);
  stats2_k<<<1, 1024, 0, stream>>>(part, (const float*)d_in[8], (const float*)d_in[9], sf);
  bn_k<0><<<4096, 256, 0, stream>>>(ybuf, sf, nullptr, P2, nullptr, nullptr);
  gemm_k<0><<<dim3(256, 2), 256, 0, stream>>>(P2, wrb + 1 * 1769472, (const float*)d_in[11],
                                              ybuf, nullptr, part);
  stats2_k<<<1, 1024, 0, stream>>>(part, (const float*)d_in[12], (const float*)d_in[13], sf);
  bn_k<1><<<4096, 256, 0, stream>>>(ybuf, sf, xt, P1, xt, nullptr);

  // resblock 2
  gemm_k<0><<<dim3(256, 2), 256, 0, stream>>>(P1, wrb + 2 * 1769472, (const float*)d_in[15],
                                              ybuf, nullptr, part);
  stats2_k<<<1, 1024, 0, stream>>>(part, (const float*)d_in[16], (const float*)d_in[17], sf);
  bn_k<0><<<4096, 256, 0, stream>>>(ybuf, sf, nullptr, P2, nullptr, nullptr);
  gemm_k<0><<<dim3(256, 2), 256, 0, stream>>>(P2, wrb + 3 * 1769472, (const float*)d_in[19],
                                              ybuf, nullptr, part);
  stats2_k<<<1, 1024, 0, stream>>>(part, (const float*)d_in[20], (const float*)d_in[21], sf);
  bn_k<2><<<4096, 256, 0, stream>>>(ybuf, sf, xt, nullptr, nullptr, r2b);

  // final: out = xm + conv1x1(res)
  gemm_k<3><<<dim3(256, 2), 256, 0, stream>>>(r2b, c8p, (const float*)d_in[23], outp,
                                              xmct, nullptr);
  aux_k<<<1, 64, 0, stream>>>(auxp, outp + 8388608);
}

// Round 6
// 713.800 us; speedup vs baseline: 1.6202x; 1.0064x over previous
//
#include <hip/hip_runtime.h>
#include <stdint.h>

typedef __attribute__((ext_vector_type(8))) short short8;
typedef __attribute__((ext_vector_type(4))) float f32x4;
typedef unsigned short u16;
typedef unsigned int u32;
typedef unsigned long long u64;

// ---------------- workspace layout (bytes) ----------------
#define WS_TOK   0ull           // tokens bf16 [32768][256]            16 MB
#define WS_XT    16777216ull    // x_t -> xm_tc -> r1 fp32 [T][C]      32 MB
#define WS_XMCT  50331648ull    // xm fp32 [C][T]                      32 MB
#define WS_GATES 83886080ull    // gw fp32 [T][2] (512KB) | tpos u32 [T][2] (512KB)
#define WS_H     84934656ull    // perm/meta/sel region (16 MB)
#define WS_P1    135266304ull   // padded bf16 [34^3][256]             19.2MB
#define WS_P2    155389952ull
#define WS_Y     175513600ull   // conv y fp32 [T][256] / earlier: eo bf16 [66560][256]
#define WS_R2    209068032ull   // r2 bf16 [T][256]
#define WS_WRB   225845248ull   // packed rb conv w bf16 [4][27][256][256]
#define WS_W1P   240001024ull
#define WS_W2P   241049600ull
#define WS_C8P   242098176ull
#define WS_PART  242229248ull   // bn partials [2][512][256] fp32 (1MB)
#define WS_SF    243277824ull   // bn scale/shift [2][256]
#define WS_AUXP  243279872ull   // aux partials [128][16]

#define WS_PERM  (WS_H + 0x00000ull)   // u32 [66560]
#define WS_TBL   (WS_H + 0x60000ull)   // u32 [520]
#define WS_META  (WS_H + 0x70000ull)   // u32 [1]
#define WS_BCNT  (WS_H + 0x80000ull)   // u32 [128][8]
#define WS_BOFF  (WS_H + 0x90000ull)   // u32 [128][8]
#define WS_SEL   (WS_H + 0x100000ull)  // u32 [32768]

__device__ __forceinline__ u16 f2bf(float f) {
  u32 x = __float_as_uint(f);
  u32 r = x + 0x7fffu + ((x >> 16) & 1u);
  return (u16)(r >> 16);
}

// ---------------- transpose x [C][T] -> x_t fp32 + tokens bf16 [T][C] ----------------
__global__ void trans_in_k(const float* __restrict__ x, float* __restrict__ xt,
                           u16* __restrict__ tok) {
  __shared__ float ld[64][65];
  int tt = blockIdx.x, cc = blockIdx.y, tid = threadIdx.x;
#pragma unroll
  for (int k = 0; k < 16; ++k) {
    int idx = tid + k * 256;
    int cl = idx >> 6, j = idx & 63;
    ld[cl][j] = x[(size_t)(cc * 64 + cl) * 32768 + tt * 64 + j];
  }
  __syncthreads();
#pragma unroll
  for (int k = 0; k < 16; ++k) {
    int idx = tid + k * 256;
    int tl = idx >> 6, cl = idx & 63;
    float v = ld[cl][tl];
    size_t o = (size_t)(tt * 64 + tl) * 256 + cc * 64 + cl;
    xt[o] = v;
    tok[o] = f2bf(v);
  }
}

// ---------------- pack resblock conv weights ----------------
__global__ void pack_rb_k(const float* __restrict__ w0, const float* __restrict__ w1,
                          const float* __restrict__ w2, const float* __restrict__ w3,
                          u16* __restrict__ out) {
  __shared__ float ld[6912];
  int conv = blockIdx.x >> 8, blk = blockIdx.x & 255, tid = threadIdx.x;
  const float* src = conv == 0 ? w0 : conv == 1 ? w1 : conv == 2 ? w2 : w3;
  size_t base = (size_t)blk * 256 * 27;
#pragma unroll
  for (int k = 0; k < 27; ++k) ld[tid + k * 256] = src[base + tid + k * 256];
  __syncthreads();
  u16* dst = out + (size_t)conv * 27 * 65536;
  int n = blk * 256 + tid;
#pragma unroll
  for (int tap = 0; tap < 27; ++tap)
    dst[(size_t)tap * 65536 + n] = f2bf(ld[tid * 27 + tap]);
}

// ---------------- transpose-pack w1/w2 256x256 matrices to [N][K] bf16 ----------------
__global__ void pack_tr_k(const float* __restrict__ w1, const float* __restrict__ w2,
                          u16* __restrict__ w1p, u16* __restrict__ w2p) {
  __shared__ float ld[64][65];
  int m = blockIdx.y, tile = blockIdx.x, tid = threadIdx.x;
  const float* src = (m < 8) ? (w1 + (size_t)m * 65536) : (w2 + (size_t)(m - 8) * 65536);
  u16* dst = (m < 8) ? (w1p + (size_t)m * 65536) : (w2p + (size_t)(m - 8) * 65536);
  int r0 = (tile >> 2) * 64, c0 = (tile & 3) * 64;
#pragma unroll
  for (int k = 0; k < 16; ++k) {
    int idx = tid + k * 256;
    int rr = idx >> 6, cc = idx & 63;
    ld[rr][cc] = src[(size_t)(r0 + rr) * 256 + c0 + cc];
  }
  __syncthreads();
#pragma unroll
  for (int k = 0; k < 16; ++k) {
    int idx = tid + k * 256;
    int cc = idx >> 6, rr = idx & 63;
    dst[(size_t)(c0 + cc) * 256 + r0 + rr] = f2bf(ld[rr][cc]);
  }
}

__global__ void cvt_k(const float* __restrict__ in, u16* __restrict__ out, int n) {
  int i = blockIdx.x * 256 + threadIdx.x;
  if (i < n) out[i] = f2bf(in[i]);
}

// ---------------- zero halo rows of both padded buffers ----------------
__global__ void halo_k(u16* __restrict__ P1, u16* __restrict__ P2) {
  int gid = blockIdx.x * 256 + threadIdx.x;
  int r = gid >> 5, o = (gid & 31) << 3;
  if (r >= 39304) return;
  int d = r / 1156, rem = r - d * 1156, h = rem / 34, w = rem - h * 34;
  if (d >= 1 && d <= 32 && h >= 1 && h <= 32 && w >= 1 && w <= 32) return;
  uint4 z = {0u, 0u, 0u, 0u};
  *(uint4*)(P1 + (size_t)r * 256 + o) = z;
  *(uint4*)(P2 + (size_t)r * 256 + o) = z;
}

// ---------------- gating: softmax + top2 + aux + sparse bookkeeping ----------------
__global__ void gate_k(const float* __restrict__ xt, const float* __restrict__ wg,
                       float* __restrict__ gw, u32* __restrict__ sel,
                       u32* __restrict__ blk_cnt, float* __restrict__ auxp) {
  __shared__ float wgs[2048];
  __shared__ float ax[4][16];
  __shared__ u32 bc[4][8];
  int tid = threadIdx.x;
#pragma unroll
  for (int k = 0; k < 8; ++k) wgs[tid + k * 256] = wg[tid + k * 256];
  __syncthreads();
  int t = blockIdx.x * 256 + tid;
  int lane = tid & 63, wv = tid >> 6;
  float l[8] = {0, 0, 0, 0, 0, 0, 0, 0};
  const float* xr = xt + (size_t)t * 256;
  for (int c = 0; c < 256; c += 4) {
    float4 xv = *(const float4*)(xr + c);
#pragma unroll
    for (int e = 0; e < 8; ++e)
      l[e] += xv.x * wgs[c * 8 + e] + xv.y * wgs[(c + 1) * 8 + e] +
              xv.z * wgs[(c + 2) * 8 + e] + xv.w * wgs[(c + 3) * 8 + e];
  }
  float mx = l[0];
#pragma unroll
  for (int e = 1; e < 8; ++e) mx = fmaxf(mx, l[e]);
  float p[8], sum = 0.f;
#pragma unroll
  for (int e = 0; e < 8; ++e) { p[e] = __expf(l[e] - mx); sum += p[e]; }
  float inv = 1.0f / sum;
#pragma unroll
  for (int e = 0; e < 8; ++e) p[e] *= inv;
  int i0 = 0; float v0 = p[0];
#pragma unroll
  for (int e = 1; e < 8; ++e) if (p[e] > v0) { v0 = p[e]; i0 = e; }
  int i1 = -1; float v1 = -1.0f;
#pragma unroll
  for (int e = 0; e < 8; ++e) if (e != i0 && p[e] > v1) { v1 = p[e]; i1 = e; }
  float wsum = v0 + v1;
  gw[t * 2] = v0 / wsum;
  gw[t * 2 + 1] = v1 / wsum;
  sel[t] = (u32)i0 | ((u32)i1 << 4);
  u64 mm[8];
#pragma unroll
  for (int e = 0; e < 8; ++e) mm[e] = __ballot(i0 == e || i1 == e);
  if (lane == 0) {
#pragma unroll
    for (int e = 0; e < 8; ++e) bc[wv][e] = (u32)__popcll(mm[e]);
  }
#pragma unroll
  for (int e = 0; e < 8; ++e) {
    float ps = p[e];
    float cn = (e == i0 || e == i1) ? 1.0f : 0.0f;
    for (int o = 32; o; o >>= 1) { ps += __shfl_down(ps, o); cn += __shfl_down(cn, o); }
    if (lane == 0) { ax[wv][e] = ps; ax[wv][8 + e] = cn; }
  }
  __syncthreads();
  if (tid < 16)
    auxp[blockIdx.x * 16 + tid] = ax[0][tid] + ax[1][tid] + ax[2][tid] + ax[3][tid];
  if (tid < 8)
    blk_cnt[blockIdx.x * 8 + tid] = bc[0][tid] + bc[1][tid] + bc[2][tid] + bc[3][tid];
}

__global__ void aux_k(const float* __restrict__ auxp, float* __restrict__ out) {
  __shared__ float s[16];
  int i = threadIdx.x;
  if (i < 16) {
    float a = 0;
    for (int b = 0; b < 128; ++b) a += auxp[b * 16 + i];
    s[i] = a;
  }
  __syncthreads();
  if (i == 0) {
    float r = 0;
    for (int e = 0; e < 8; ++e)
      r += (s[8 + e] * (1.0f / 32768.0f)) * (s[e] * (1.0f / 32768.0f));
    out[0] = r * 8.0f;
  }
}

// ---------------- scan: block counts -> absolute offsets, chunk table, perm pads ----
__global__ void scan_k(const u32* __restrict__ blk_cnt, u32* __restrict__ blkoff,
                       u32* __restrict__ tbl, u32* __restrict__ meta,
                       u32* __restrict__ perm) {
  __shared__ u32 tot[8], base[8], nck[8], cbase[8];
  int tid = threadIdx.x;
  if (tid < 8) {
    u32 run = 0;
    for (int b = 0; b < 128; ++b) {
      blkoff[b * 8 + tid] = run;
      run += blk_cnt[b * 8 + tid];
    }
    tot[tid] = run;
  }
  __syncthreads();
  if (tid == 0) {
    u32 acc = 0, c = 0;
    for (int e = 0; e < 8; ++e) {
      base[e] = acc;
      u32 nc = (tot[e] + 127) >> 7;
      nck[e] = nc;
      cbase[e] = c;
      acc += nc << 7;
      c += nc;
    }
    meta[0] = c;
  }
  __syncthreads();
  for (int i = tid; i < 1024; i += 256) blkoff[i] += base[i & 7];
  if (tid < 8) {
    for (u32 k = 0; k < nck[tid]; ++k)
      tbl[cbase[tid] + k] = ((base[tid] + (k << 7)) << 4) | (u32)tid;
    for (u32 sl = base[tid] + tot[tid]; sl < base[tid] + (nck[tid] << 7); ++sl)
      perm[sl] = 0;
  }
}

// ---------------- scatter: deterministic positions via ballot ranks ----------------
__global__ void scatter_k(const u32* __restrict__ sel, const u32* __restrict__ blkoff,
                          u32* __restrict__ perm, u32* __restrict__ tpos) {
  __shared__ u32 wcnt[4][8];
  int tid = threadIdx.x, b = blockIdx.x;
  int lane = tid & 63, wv = tid >> 6;
  int t = b * 256 + tid;
  u32 s = sel[t];
  int i0 = s & 15, i1 = (s >> 4) & 15;
  u64 mm[8];
#pragma unroll
  for (int e = 0; e < 8; ++e) mm[e] = __ballot(i0 == e || i1 == e);
  if (lane == 0) {
#pragma unroll
    for (int e = 0; e < 8; ++e) wcnt[wv][e] = (u32)__popcll(mm[e]);
  }
  __syncthreads();
  u64 lt = (1ull << lane) - 1ull;
#pragma unroll
  for (int e = 0; e < 8; ++e) {
    bool is0 = (i0 == e), is1 = (i1 == e);
    if (is0 || is1) {
      u32 woff = 0;
#pragma unroll
      for (int w = 0; w < 4; ++w)
        if (w < wv) woff += wcnt[w][e];
      u32 pos = blkoff[b * 8 + e] + woff + (u32)__popcll(mm[e] & lt);
      perm[pos] = (u32)t;
      tpos[t * 2 + (is0 ? 0 : 1)] = pos;
    }
  }
}

// ---------------- sparse MoE GEMM: one expert-chunk of 128 gathered tokens ----------
__global__ __launch_bounds__(512, 2) void moe_gemm_k(
    const u16* __restrict__ tok, const u32* __restrict__ perm,
    const u32* __restrict__ tbl, const u32* __restrict__ meta,
    const u16* __restrict__ w1p, const u16* __restrict__ w2p,
    const float* __restrict__ b1, const float* __restrict__ b2,
    u16* __restrict__ eo) {
  __shared__ __attribute__((aligned(16))) unsigned char smem[163840];
  const int bid = blockIdx.x;
  if ((u32)bid >= meta[0]) return;
  const u32 ent = tbl[bid];
  const int e = (int)(ent & 15u);
  const int slot0 = (int)(ent >> 4);
  const int tid = threadIdx.x;
  const int lane = tid & 63;
  const int wv = tid >> 6;
  const int wr = (wv >> 2) * 64;
  const int wc = (wv & 3) * 64;
  const int fq = lane >> 4, fr = lane & 15;
  const u16* w1e = w1p + e * 65536;
  const u16* w2e = w2p + e * 65536;

#pragma unroll
  for (int it = 0; it < 8; ++it) {
    int s = tid + it * 512;
    int r = s >> 5, seg = s & 31;
    int cole = ((seg >> 3) << 6) + (((seg & 7) ^ (r & 7)) << 3);
    u32 rowtok = perm[slot0 + r];
    __builtin_amdgcn_global_load_lds(
        (const __attribute__((address_space(1))) u32*)(tok + (size_t)rowtok * 256 + cole),
        (__attribute__((address_space(3))) u32*)(smem + s * 16), 16, 0, 0);
  }

  f32x4 acc1[4][4];
#pragma unroll
  for (int mc = 0; mc < 4; ++mc)
#pragma unroll
    for (int nt = 0; nt < 4; ++nt) acc1[mc][nt] = (f32x4){0.f, 0.f, 0.f, 0.f};

#pragma unroll 1
  for (int kc = 0; kc < 4; ++kc) {
#pragma unroll
    for (int it = 0; it < 4; ++it) {
      int s = tid + it * 512;
      int r = s >> 3;
      int sub = (s & 7) ^ (r & 7);
      __builtin_amdgcn_global_load_lds(
          (const __attribute__((address_space(1))) u32*)(w1e + (size_t)r * 256 + kc * 64 + sub * 8),
          (__attribute__((address_space(3))) u32*)(smem + 65536 + s * 16), 16, 0, 0);
    }
    __syncthreads();
#pragma unroll
    for (int khf = 0; khf < 2; ++khf) {
      short8 af1[4], bt[4];
#pragma unroll
      for (int mc = 0; mc < 4; ++mc) {
        int row = wc + mc * 16 + fr;
        int p = (khf * 4 + fq) ^ (row & 7);
        af1[mc] = *(const short8*)(smem + 65536 + row * 128 + p * 16);
      }
#pragma unroll
      for (int nt = 0; nt < 4; ++nt) {
        int row = wr + nt * 16 + fr;
        int p = (khf * 4 + fq) ^ (row & 7);
        bt[nt] = *(const short8*)(smem + row * 512 + kc * 128 + p * 16);
      }
#pragma unroll
      for (int mc = 0; mc < 4; ++mc)
#pragma unroll
        for (int nt = 0; nt < 4; ++nt)
          acc1[mc][nt] = __builtin_amdgcn_mfma_f32_16x16x32_bf16(af1[mc], bt[nt], acc1[mc][nt], 0, 0, 0);
    }
    __syncthreads();
  }

#pragma unroll
  for (int mc = 0; mc < 4; ++mc) {
    int k0 = wc + mc * 16 + fq * 4;
    float4 bv = *(const float4*)(b1 + e * 256 + k0);
#pragma unroll
    for (int nt = 0; nt < 4; ++nt) {
      int t = wr + nt * 16 + fr;
      u64 pk = 0;
#pragma unroll
      for (int j = 0; j < 4; ++j) {
        float v = acc1[mc][nt][j] + ((const float*)&bv)[j];
        float u = 1.5957691216057308f * (v + 0.044715f * v * v * v);
        float g = v / (1.0f + __expf(-u));
        pk |= (u64)f2bf(g) << (16 * j);
      }
      *(u64*)(smem + 98304 + t * 512 + ((k0 * 2) ^ ((t & 7) << 4))) = pk;
    }
  }

  f32x4 acc2[4][4];
#pragma unroll
  for (int m = 0; m < 4; ++m)
#pragma unroll
    for (int n = 0; n < 4; ++n) acc2[m][n] = (f32x4){0.f, 0.f, 0.f, 0.f};

#pragma unroll 1
  for (int kc = 0; kc < 4; ++kc) {
#pragma unroll
    for (int it = 0; it < 4; ++it) {
      int s = tid + it * 512;
      int r = s >> 3;
      int sub = (s & 7) ^ (r & 7);
      __builtin_amdgcn_global_load_lds(
          (const __attribute__((address_space(1))) u32*)(w2e + (size_t)r * 256 + kc * 64 + sub * 8),
          (__attribute__((address_space(3))) u32*)(smem + 65536 + s * 16), 16, 0, 0);
    }
    __syncthreads();
#pragma unroll
    for (int khf = 0; khf < 2; ++khf) {
      short8 af[4], bb[4];
#pragma unroll
      for (int m = 0; m < 4; ++m) {
        int row = wr + m * 16 + fr;
        int col = (kc * 128 + (khf * 4 + fq) * 16) ^ ((row & 7) << 4);
        af[m] = *(const short8*)(smem + 98304 + row * 512 + col);
      }
#pragma unroll
      for (int n = 0; n < 4; ++n) {
        int row = wc + n * 16 + fr;
        int p = (khf * 4 + fq) ^ (row & 7);
        bb[n] = *(const short8*)(smem + 65536 + row * 128 + p * 16);
      }
#pragma unroll
      for (int m = 0; m < 4; ++m)
#pragma unroll
        for (int n = 0; n < 4; ++n)
          acc2[m][n] = __builtin_amdgcn_mfma_f32_16x16x32_bf16(af[m], bb[n], acc2[m][n], 0, 0, 0);
    }
    __syncthreads();
  }

  float bs2[4];
#pragma unroll
  for (int n = 0; n < 4; ++n) bs2[n] = b2[e * 256 + wc + n * 16 + fr];
#pragma unroll
  for (int m = 0; m < 4; ++m)
#pragma unroll
    for (int j = 0; j < 4; ++j) {
      int rowslot = slot0 + wr + m * 16 + fq * 4 + j;
      u16* er = eo + (size_t)rowslot * 256 + wc;
#pragma unroll
      for (int n = 0; n < 4; ++n) er[n * 16 + fr] = f2bf(acc2[m][n][j] + bs2[n]);
    }
}

// ---------------- combine: xm = x + g0*eo[p0] + g1*eo[p1]; write xt/xmct/pad --------
__global__ void combine_k(float* __restrict__ xt, const u16* __restrict__ eo,
                          const float* __restrict__ gw, const u32* __restrict__ tpos,
                          float* __restrict__ xmct, u16* __restrict__ pad) {
  __shared__ float ld[64][65];
  __shared__ u32 pp[64][2];
  __shared__ float gg[64][2];
  int tt = blockIdx.x, cc = blockIdx.y, tid = threadIdx.x;
  if (tid < 128) {
    int tl = tid >> 1, s = tid & 1;
    int t = tt * 64 + tl;
    pp[tl][s] = tpos[t * 2 + s];
    gg[tl][s] = gw[t * 2 + s];
  }
  __syncthreads();
#pragma unroll
  for (int k = 0; k < 16; ++k) {
    int idx = tid + k * 256;
    int tl = idx >> 6, cl = idx & 63;
    int c = cc * 64 + cl;
    size_t o = (size_t)(tt * 64 + tl) * 256 + c;
    float e0 = __uint_as_float((u32)eo[(size_t)pp[tl][0] * 256 + c] << 16);
    float e1 = __uint_as_float((u32)eo[(size_t)pp[tl][1] * 256 + c] << 16);
    float v = xt[o] + gg[tl][0] * e0 + gg[tl][1] * e1;
    xt[o] = v;
    ld[tl][cl] = v;
    int t = tt * 64 + tl;
    int d = t >> 10, h = (t >> 5) & 31, w = t & 31;
    int prow = (d + 1) * 1156 + (h + 1) * 34 + (w + 1);
    pad[(size_t)prow * 256 + c] = f2bf(v);
  }
  __syncthreads();
#pragma unroll
  for (int k = 0; k < 16; ++k) {
    int idx = tid + k * 256;
    int cl = idx >> 6, tl = idx & 63;
    xmct[(size_t)(cc * 64 + cl) * 32768 + tt * 64 + tl] = ld[tl][cl];
  }
}

// ---------------- unified MFMA GEMM (convs + final 1x1), 2-phase double-buffer ------
// MODE 0: conv3x3x3 from padded buffer (XCD-swizzled ttile), y fp32 + BN partials
// MODE 3: final 1x1 conv, out[oc][t] = acc + bias + xmct[oc][t]
// LDS: 2 x (A 16KB | B 16KB) = 64KB. Per step: issue next-step's 8 global_load_lds,
// compute current from LDS, then vmcnt(0) + raw s_barrier (loads overlap compute).
template <int MODE>
__global__ __launch_bounds__(256, 2) void gemm_k(
    const u16* __restrict__ A, const u16* __restrict__ Bw,
    const float* __restrict__ bias, float* __restrict__ outF,
    const float* __restrict__ xmct, float* __restrict__ part) {
  __shared__ __attribute__((aligned(16))) unsigned char smem[65536];
  const int tid = threadIdx.x;
  const int bx = blockIdx.x;
  const int ttile = (MODE == 0) ? ((bx & 7) * 32 + (bx >> 3)) : bx;  // XCD-bijective
  const int ctile = blockIdx.y;
  const int lane = tid & 63;
  const int wv = tid >> 6;
  const int wr = (wv >> 1) << 6;
  const int wc = (wv & 1) << 6;
  const int fq = lane >> 4;
  const int fr = lane & 15;

  int aoff[4], boff[4];
#pragma unroll
  for (int it = 0; it < 4; ++it) {
    int s = tid + it * 256;
    int r = s >> 3;
    int lsg = (s & 7) ^ (r & 7);
    if (MODE == 0) {
      int dd = ttile >> 3;
      int h0 = (ttile & 7) << 2;
      int base = dd * 1156 + (h0 + (r >> 5)) * 34 + (r & 31);
      aoff[it] = base * 256 + lsg * 8;
    } else {
      aoff[it] = (ttile * 128 + r) * 256 + lsg * 8;
    }
    boff[it] = (ctile * 128 + r) * 256 + lsg * 8;
  }

  f32x4 acc[4][4];
#pragma unroll
  for (int m = 0; m < 4; ++m)
#pragma unroll
    for (int n = 0; n < 4; ++n) acc[m][n] = (f32x4){0.f, 0.f, 0.f, 0.f};

  const int nStep = (MODE == 0) ? 108 : 4;  // step = tap*4 + kc

  // stage step s into buffer buf
  auto stage = [&](int s, int buf) {
    int tap = (MODE == 0) ? (s >> 2) : 0;
    int kc = s & 3;
    int atap = 0, btap = 0;
    if (MODE == 0) {
      atap = ((tap / 9) * 1156 + ((tap / 3) % 3) * 34 + (tap % 3)) * 256;
      btap = tap * 65536;
    }
    const u16* Ak = A + atap + kc * 64;
    const u16* Bk = Bw + btap + kc * 64;
    unsigned char* sb = smem + buf * 32768;
#pragma unroll
    for (int it = 0; it < 4; ++it) {
      __builtin_amdgcn_global_load_lds(
          (const __attribute__((address_space(1))) u32*)(Ak + aoff[it]),
          (__attribute__((address_space(3))) u32*)(sb + (tid + it * 256) * 16),
          16, 0, 0);
      __builtin_amdgcn_global_load_lds(
          (const __attribute__((address_space(1))) u32*)(Bk + boff[it]),
          (__attribute__((address_space(3))) u32*)(sb + 16384 + (tid + it * 256) * 16),
          16, 0, 0);
    }
  };

  auto compute = [&](int buf) {
    unsigned char* sb = smem + buf * 32768;
#pragma unroll
    for (int khf = 0; khf < 2; ++khf) {
      short8 af[4], bb[4];
#pragma unroll
      for (int m = 0; m < 4; ++m) {
        int row = wr + m * 16 + fr;
        int p = (khf * 4 + fq) ^ (row & 7);
        af[m] = *(const short8*)(sb + row * 128 + p * 16);
      }
#pragma unroll
      for (int n = 0; n < 4; ++n) {
        int row = wc + n * 16 + fr;
        int p = (khf * 4 + fq) ^ (row & 7);
        bb[n] = *(const short8*)(sb + 16384 + row * 128 + p * 16);
      }
#pragma unroll
      for (int m = 0; m < 4; ++m)
#pragma unroll
        for (int n = 0; n < 4; ++n)
          acc[m][n] = __builtin_amdgcn_mfma_f32_16x16x32_bf16(af[m], bb[n], acc[m][n], 0, 0, 0);
    }
  };

  stage(0, 0);
  asm volatile("s_waitcnt vmcnt(0)" ::: "memory");
  __builtin_amdgcn_s_barrier();
  int cur = 0;
#pragma unroll 1
  for (int s = 0; s < nStep; ++s) {
    if (s + 1 < nStep) stage(s + 1, cur ^ 1);
    compute(cur);
    asm volatile("s_waitcnt vmcnt(0)" ::: "memory");
    __builtin_amdgcn_s_barrier();
    cur ^= 1;
  }

  float bs[4];
#pragma unroll
  for (int n = 0; n < 4; ++n) bs[n] = bias[ctile * 128 + wc + n * 16 + fr];

  if (MODE == 3) {
#pragma unroll
    for (int m = 0; m < 4; ++m) {
      int trow = ttile * 128 + wr + m * 16 + fq * 4;
#pragma unroll
      for (int n = 0; n < 4; ++n) {
        int oc = ctile * 128 + wc + n * 16 + fr;
        size_t o = (size_t)oc * 32768 + trow;
        float4 xv = *(const float4*)(xmct + o);
        float4 w;
        w.x = acc[m][n][0] + bs[n] + xv.x;
        w.y = acc[m][n][1] + bs[n] + xv.y;
        w.z = acc[m][n][2] + bs[n] + xv.z;
        w.w = acc[m][n][3] + bs[n] + xv.w;
        *(float4*)(outF + o) = w;
      }
    }
  } else {
    float sn[4] = {0, 0, 0, 0}, qn[4] = {0, 0, 0, 0};
#pragma unroll
    for (int m = 0; m < 4; ++m) {
#pragma unroll
      for (int j = 0; j < 4; ++j) {
        int t = ttile * 128 + wr + m * 16 + fq * 4 + j;
        float* yr = outF + (size_t)t * 256 + ctile * 128 + wc;
#pragma unroll
        for (int n = 0; n < 4; ++n) {
          float v = acc[m][n][j] + bs[n];
          yr[n * 16 + fr] = v;
          sn[n] += v;
          qn[n] += v * v;
        }
      }
    }
#pragma unroll
    for (int n = 0; n < 4; ++n) {
      float s = sn[n], q = qn[n];
      s += __shfl_xor(s, 16); s += __shfl_xor(s, 32);
      q += __shfl_xor(q, 16); q += __shfl_xor(q, 32);
      if (lane < 16) {
        int pi = (ttile * 2 + (wv >> 1)) * 256 + ctile * 128 + wc + n * 16 + fr;
        part[pi] = s;
        part[131072 + pi] = q;
      }
    }
  }
}

// ---------------- BN stats reduce ----------------
__global__ void stats2_k(const float* __restrict__ part, const float* __restrict__ g,
                         const float* __restrict__ be, float* __restrict__ sf) {
  __shared__ float sred[4][256], qred[4][256];
  int tid = threadIdx.x;
  int c = tid & 255, qd = tid >> 8;
  float s = 0, q = 0;
  for (int b = qd * 128; b < qd * 128 + 128; ++b) {
    s += part[b * 256 + c];
    q += part[131072 + b * 256 + c];
  }
  sred[qd][c] = s;
  qred[qd][c] = q;
  __syncthreads();
  if (qd == 0) {
    s = sred[0][c] + sred[1][c] + sred[2][c] + sred[3][c];
    q = qred[0][c] + qred[1][c] + qred[2][c] + qred[3][c];
    float mean = s * (1.0f / 32768.0f);
    float var = q * (1.0f / 32768.0f) - mean * mean;
    float a = g[c] * rsqrtf(var + 1e-5f);
    sf[c] = a;
    sf[256 + c] = be[c] - mean * a;
  }
}

// ---------------- BN apply (+leaky, +skip) ----------------
template <int V>
__global__ void bn_k(const float* __restrict__ y, const float* __restrict__ sf,
                     const float* __restrict__ skip, u16* __restrict__ pad,
                     float* __restrict__ f32o, u16* __restrict__ bfo) {
  int gid = blockIdx.x * 256 + threadIdx.x;
  int t = gid >> 5, c0 = (gid & 31) << 3;
  size_t base = (size_t)t * 256 + c0;
  float v[8];
  const float4* yp = (const float4*)(y + base);
  float4 y0 = yp[0], y1 = yp[1];
  const float4* ap = (const float4*)(sf + c0);
  float4 a0 = ap[0], a1 = ap[1];
  const float4* shp = (const float4*)(sf + 256 + c0);
  float4 s0 = shp[0], s1 = shp[1];
  v[0] = a0.x * y0.x + s0.x; v[1] = a0.y * y0.y + s0.y;
  v[2] = a0.z * y0.z + s0.z; v[3] = a0.w * y0.w + s0.w;
  v[4] = a1.x * y1.x + s1.x; v[5] = a1.y * y1.y + s1.y;
  v[6] = a1.z * y1.z + s1.z; v[7] = a1.w * y1.w + s1.w;
  if (V >= 1) {
    const float4* kp = (const float4*)(skip + base);
    float4 k0 = kp[0], k1 = kp[1];
    v[0] += k0.x; v[1] += k0.y; v[2] += k0.z; v[3] += k0.w;
    v[4] += k1.x; v[5] += k1.y; v[6] += k1.z; v[7] += k1.w;
  }
#pragma unroll
  for (int i = 0; i < 8; ++i) v[i] = v[i] > 0.0f ? v[i] : 0.01f * v[i];
  if (V <= 1) {
    int d = t >> 10, h = (t >> 5) & 31, w = t & 31;
    int prow = (d + 1) * 1156 + (h + 1) * 34 + (w + 1);
    uint4 pk;
    pk.x = (u32)f2bf(v[0]) | ((u32)f2bf(v[1]) << 16);
    pk.y = (u32)f2bf(v[2]) | ((u32)f2bf(v[3]) << 16);
    pk.z = (u32)f2bf(v[4]) | ((u32)f2bf(v[5]) << 16);
    pk.w = (u32)f2bf(v[6]) | ((u32)f2bf(v[7]) << 16);
    *(uint4*)(pad + (size_t)prow * 256 + c0) = pk;
  }
  if (V == 1) {
    float4 o0 = {v[0], v[1], v[2], v[3]}, o1 = {v[4], v[5], v[6], v[7]};
    float4* fp = (float4*)(f32o + base);
    fp[0] = o0; fp[1] = o1;
  }
  if (V == 2) {
    uint4 pk;
    pk.x = (u32)f2bf(v[0]) | ((u32)f2bf(v[1]) << 16);
    pk.y = (u32)f2bf(v[2]) | ((u32)f2bf(v[3]) << 16);
    pk.z = (u32)f2bf(v[4]) | ((u32)f2bf(v[5]) << 16);
    pk.w = (u32)f2bf(v[6]) | ((u32)f2bf(v[7]) << 16);
    *(uint4*)(bfo + base) = pk;
  }
}

extern "C" void kernel_launch(void* const* d_in, const int* in_sizes, int n_in,
                              void* d_out, int out_size, void* d_ws, size_t ws_size,
                              hipStream_t stream) {
  (void)in_sizes; (void)n_in; (void)out_size; (void)ws_size;
  const float* x  = (const float*)d_in[0];
  const float* wg = (const float*)d_in[1];
  const float* w1 = (const float*)d_in[2];
  const float* b1 = (const float*)d_in[3];
  const float* w2 = (const float*)d_in[4];
  const float* b2 = (const float*)d_in[5];

  char* ws = (char*)d_ws;
  u16* tok    = (u16*)(ws + WS_TOK);
  float* xt   = (float*)(ws + WS_XT);
  float* xmct = (float*)(ws + WS_XMCT);
  float* gw   = (float*)(ws + WS_GATES);
  u32* tpos   = (u32*)(ws + WS_GATES + 0x80000ull);
  u32* perm   = (u32*)(ws + WS_PERM);
  u32* tbl    = (u32*)(ws + WS_TBL);
  u32* meta   = (u32*)(ws + WS_META);
  u32* bcnt   = (u32*)(ws + WS_BCNT);
  u32* boff   = (u32*)(ws + WS_BOFF);
  u32* selb   = (u32*)(ws + WS_SEL);
  u16* P1     = (u16*)(ws + WS_P1);
  u16* P2     = (u16*)(ws + WS_P2);
  float* ybuf = (float*)(ws + WS_Y);
  u16* eo     = (u16*)(ws + WS_Y);   // eo lives in Y before convs start
  u16* r2b    = (u16*)(ws + WS_R2);
  u16* wrb    = (u16*)(ws + WS_WRB);
  u16* w1p    = (u16*)(ws + WS_W1P);
  u16* w2p    = (u16*)(ws + WS_W2P);
  u16* c8p    = (u16*)(ws + WS_C8P);
  float* part = (float*)(ws + WS_PART);
  float* sf   = (float*)(ws + WS_SF);
  float* auxp = (float*)(ws + WS_AUXP);
  float* outp = (float*)d_out;

  halo_k<<<4913, 256, 0, stream>>>(P1, P2);
  trans_in_k<<<dim3(512, 4), 256, 0, stream>>>(x, xt, tok);
  pack_rb_k<<<1024, 256, 0, stream>>>((const float*)d_in[6], (const float*)d_in[10],
                                      (const float*)d_in[14], (const float*)d_in[18], wrb);
  pack_tr_k<<<dim3(16, 16), 256, 0, stream>>>(w1, w2, w1p, w2p);
  cvt_k<<<256, 256, 0, stream>>>((const float*)d_in[22], c8p, 65536);

  gate_k<<<128, 256, 0, stream>>>(xt, wg, gw, selb, bcnt, auxp);
  scan_k<<<1, 256, 0, stream>>>(bcnt, boff, tbl, meta, perm);
  scatter_k<<<128, 256, 0, stream>>>(selb, boff, perm, tpos);
  moe_gemm_k<<<520, 512, 0, stream>>>(tok, perm, tbl, meta, w1p, w2p, b1, b2, eo);
  combine_k<<<dim3(512, 4), 256, 0, stream>>>(xt, eo, gw, tpos, xmct, P1);

  // resblock 1
  gemm_k<0><<<dim3(256, 2), 256, 0, stream>>>(P1, wrb + 0 * 1769472, (const float*)d_in[7],
                                              ybuf, nullptr, part);
  stats2_k<<<1, 1024, 0, stream>>>(part, (const float*)d_in[8], (const float*)d_in[9], sf);
  bn_k<0><<<4096, 256, 0, stream>>>(ybuf, sf, nullptr, P2, nullptr, nullptr);
  gemm_k<0><<<dim3(256, 2), 256, 0, stream>>>(P2, wrb + 1 * 1769472, (const float*)d_in[11],
                                              ybuf, nullptr, part);
  stats2_k<<<1, 1024, 0, stream>>>(part, (const float*)d_in[12], (const float*)d_in[13], sf);
  bn_k<1><<<4096, 256, 0, stream>>>(ybuf, sf, xt, P1, xt, nullptr);

  // resblock 2
  gemm_k<0><<<dim3(256, 2), 256, 0, stream>>>(P1, wrb + 2 * 1769472, (const float*)d_in[15],
                                              ybuf, nullptr, part);
  stats2_k<<<1, 1024, 0, stream>>>(part, (const float*)d_in[16], (const float*)d_in[17], sf);
  bn_k<0><<<4096, 256, 0, stream>>>(ybuf, sf, nullptr, P2, nullptr, nullptr);
  gemm_k<0><<<dim3(256, 2), 256, 0, stream>>>(P2, wrb + 3 * 1769472, (const float*)d_in[19],
                                              ybuf, nullptr, part);
  stats2_k<<<1, 1024, 0, stream>>>(part, (const float*)d_in[20], (const float*)d_in[21], sf);
  bn_k<2><<<4096, 256, 0, stream>>>(ybuf, sf, xt, nullptr, nullptr, r2b);

  // final: out = xm + conv1x1(res)
  gemm_k<3><<<dim3(256, 2), 256, 0, stream>>>(r2b, c8p, (const float*)d_in[23], outp,
                                              xmct, nullptr);
  aux_k<<<1, 64, 0, stream>>>(auxp, outp + 8388608);
}